// Round 5
// baseline (328.658 us; speedup 1.0000x reference)
//
#include <hip/hip_runtime.h>
#include <hip/hip_bf16.h>

// ---------------------------------------------------------------------------
// SAGE-GCN x3 on MI355X.  Round 5.
//   CSR build: bucketed 2-pass (round 4; killed k_fill's 16x write amp).
//   Agg: feature-QUARTER split (64B chunks) pinned to XCDs via blockIdx&3 so
//     each XCD's gather working set (3.2 MB) fits its 4 MB L2.  Round-4
//     evidence: half split (6.4 MB/XCD) thrashed -> FETCH 157 MB, 51.6 us.
//   Wave = 16 feature-lanes x 4 edge-groups per node; shfl_xor reduce.
//   esrc stored as ushort (n <= 65536) to halve the edge-list stream.
//   GEMM: MFMA 16x16x32 bf16 (round 3).
// ---------------------------------------------------------------------------

#define NFEAT 128
#define BKT_CAP 12288   // per-bucket pair capacity (avg ~8163 @ n=50000)

using bf16x8 = __attribute__((ext_vector_type(8))) short;
using f32x4  = __attribute__((ext_vector_type(4))) float;

__device__ __forceinline__ ushort f2bf(float f) {
    unsigned u = __float_as_uint(f);
    u = (u + 0x7fffu + ((u >> 16) & 1u)) >> 16;
    return (ushort)u;
}
__device__ __forceinline__ float bflo(unsigned v) { return __uint_as_float(v << 16); }
__device__ __forceinline__ float bfhi(unsigned v) { return __uint_as_float(v & 0xffff0000u); }

// ---------------- CSR build ----------------

__global__ __launch_bounds__(128) void k_zero128(int* __restrict__ p) {
    p[threadIdx.x] = 0;
}

// Pass A: bin edges into 512-node buckets; block-aggregated cursor alloc.
__global__ __launch_bounds__(256) void k_bin(const int* __restrict__ src, const int* __restrict__ dst,
                                             int* __restrict__ gcur, unsigned* __restrict__ pairs, int ne) {
    __shared__ int lcnt[128];
    __shared__ int lbase[128];
    int tid = threadIdx.x;
    if (tid < 128) lcnt[tid] = 0;
    __syncthreads();
    int e0 = blockIdx.x * 4096;
    int myrank[16];
    int mybkt[16];
    unsigned mypair[16];
    #pragma unroll
    for (int i = 0; i < 16; ++i) {
        int e = e0 + tid + i * 256;
        if (e < ne) {
            int s = src[e], d = dst[e];
            int b = d >> 9;
            mybkt[i]  = b;
            mypair[i] = (unsigned)(s & 0xffff) | ((unsigned)(d & 511) << 16);
            myrank[i] = atomicAdd(&lcnt[b], 1);
        } else mybkt[i] = -1;
    }
    __syncthreads();
    if (tid < 128) lbase[tid] = lcnt[tid] ? atomicAdd(&gcur[tid], lcnt[tid]) : 0;
    __syncthreads();
    #pragma unroll
    for (int i = 0; i < 16; ++i) {
        if (mybkt[i] >= 0) {
            int pos = lbase[mybkt[i]] + myrank[i];
            if (pos < BKT_CAP) pairs[(size_t)mybkt[i] * BKT_CAP + pos] = mypair[i];
        }
    }
}

// Pass B1: per-bucket per-node counts, written coalesced.
__global__ __launch_bounds__(256) void k_cnt(const unsigned* __restrict__ pairs, const int* __restrict__ gcur,
                                             int* __restrict__ cnt, int n) {
    __shared__ int lcnt[512];
    int b = blockIdx.x, tid = threadIdx.x;
    for (int i = tid; i < 512; i += 256) lcnt[i] = 0;
    __syncthreads();
    int m = gcur[b];
    if (m > BKT_CAP) m = BKT_CAP;
    const unsigned* p = pairs + (size_t)b * BKT_CAP;
    for (int i = tid; i < m; i += 256) atomicAdd(&lcnt[p[i] >> 16], 1);
    __syncthreads();
    int base = b * 512;
    for (int i = tid; i < 512; i += 256) {
        int node = base + i;
        if (node < n) cnt[node] = lcnt[i];
    }
}

// hierarchical scan: cnt -> offs
__global__ __launch_bounds__(1024) void k_scan_part(const int* __restrict__ cnt, int* __restrict__ part,
                                                    int* __restrict__ tots, int n) {
    __shared__ int wtot[16];
    __shared__ int wpre[16];
    int tid  = threadIdx.x;
    int lane = tid & 63;
    int wv   = tid >> 6;
    int i    = blockIdx.x * 1024 + tid;
    int v    = (i < n) ? cnt[i] : 0;
    int val  = v;
    #pragma unroll
    for (int off = 1; off < 64; off <<= 1) {
        int t = __shfl_up(val, off);
        if (lane >= off) val += t;
    }
    if (lane == 63) wtot[wv] = val;
    __syncthreads();
    if (tid == 0) {
        int s = 0;
        #pragma unroll
        for (int w = 0; w < 16; ++w) { wpre[w] = s; s += wtot[w]; }
        tots[blockIdx.x] = s;
    }
    __syncthreads();
    int excl = val - v + wpre[wv];
    if (i < n) part[i] = excl;
}

__global__ __launch_bounds__(1024) void k_scan_tops(int* __restrict__ tots, int* __restrict__ total_out, int nch) {
    __shared__ int wtot[16];
    __shared__ int wpre[16];
    int tid  = threadIdx.x;
    int lane = tid & 63;
    int wv   = tid >> 6;
    int v    = (tid < nch) ? tots[tid] : 0;
    int val  = v;
    #pragma unroll
    for (int off = 1; off < 64; off <<= 1) {
        int t = __shfl_up(val, off);
        if (lane >= off) val += t;
    }
    if (lane == 63) wtot[wv] = val;
    __syncthreads();
    if (tid == 0) {
        int s = 0;
        #pragma unroll
        for (int w = 0; w < 16; ++w) { wpre[w] = s; s += wtot[w]; }
        *total_out = s;
    }
    __syncthreads();
    int excl = val - v + wpre[wv];
    if (tid < nch) tots[tid] = excl;
}

__global__ __launch_bounds__(1024) void k_scan_add(int* __restrict__ offs, const int* __restrict__ tots, int n) {
    int i = blockIdx.x * 1024 + threadIdx.x;
    if (i < n) offs[i] += tots[blockIdx.x];
}

// Pass B2: per-bucket scatter into esrc (ushort; one block per bucket).
__global__ __launch_bounds__(256) void k_scatter(const unsigned* __restrict__ pairs, const int* __restrict__ gcur,
                                                 const int* __restrict__ offs, ushort* __restrict__ esrc, int n) {
    __shared__ int lcur[512];
    __shared__ int loffs[512];
    int b = blockIdx.x, tid = threadIdx.x;
    int base = b * 512;
    for (int i = tid; i < 512; i += 256) {
        lcur[i] = 0;
        int node = base + i;
        loffs[i] = (node < n) ? offs[node] : 0;
    }
    __syncthreads();
    int m = gcur[b];
    if (m > BKT_CAP) m = BKT_CAP;
    const unsigned* p = pairs + (size_t)b * BKT_CAP;
    for (int i = tid; i < m; i += 256) {
        unsigned pr = p[i];
        int dlow = pr >> 16;
        int r = atomicAdd(&lcur[dlow], 1);
        esrc[loffs[dlow] + r] = (ushort)(pr & 0xffffu);
    }
}

// ---------------- cast W0|W1|W2 -> bf16 ----------------

__global__ __launch_bounds__(256) void k_cast3(const float* __restrict__ a, int na,
                                               const float* __restrict__ b, int nb,
                                               const float* __restrict__ c, int nc,
                                               ushort* __restrict__ out) {
    int i = blockIdx.x * 256 + threadIdx.x;
    if (i >= na + nb + nc) return;
    float v = (i < na) ? a[i] : ((i < na + nb) ? b[i - na] : c[i - na - nb]);
    out[i] = f2bf(v);
}

// ---------------- GEMM: Y_bf16[M][N] = X[M][128] @ Wb[N][128]^T ----------------

template <typename InT, int N>
__global__ __launch_bounds__(256) void k_gemm_mfma(const InT* __restrict__ X, const ushort* __restrict__ Wb,
                                                   ushort* __restrict__ Y, int M) {
    int w    = threadIdx.x >> 6;
    int lane = threadIdx.x & 63;
    int rowf = blockIdx.x * 64 + w * 16 + (lane & 15);
    int kb   = (lane >> 4) * 8;

    bf16x8 a[4];
    if (rowf < M) {
        #pragma unroll
        for (int ks = 0; ks < 4; ++ks) {
            if constexpr (sizeof(InT) == 2) {
                a[ks] = *(const bf16x8*)((const ushort*)X + (size_t)rowf * 128 + ks * 32 + kb);
            } else {
                const float* xp = (const float*)X + (size_t)rowf * 128 + ks * 32 + kb;
                float4 f0 = *(const float4*)xp;
                float4 f1 = *(const float4*)(xp + 4);
                bf16x8 t;
                t[0] = f2bf(f0.x); t[1] = f2bf(f0.y); t[2] = f2bf(f0.z); t[3] = f2bf(f0.w);
                t[4] = f2bf(f1.x); t[5] = f2bf(f1.y); t[6] = f2bf(f1.z); t[7] = f2bf(f1.w);
                a[ks] = t;
            }
        }
    } else {
        #pragma unroll
        for (int ks = 0; ks < 4; ++ks) {
            bf16x8 z = {0, 0, 0, 0, 0, 0, 0, 0};
            a[ks] = z;
        }
    }

    constexpr int NT = N / 16;
    f32x4 acc[NT];
    #pragma unroll
    for (int nt = 0; nt < NT; ++nt) acc[nt] = (f32x4){0.f, 0.f, 0.f, 0.f};

    #pragma unroll
    for (int nt = 0; nt < NT; ++nt) {
        const ushort* wp = Wb + (size_t)(nt * 16 + (lane & 15)) * 128 + kb;
        #pragma unroll
        for (int ks = 0; ks < 4; ++ks) {
            bf16x8 b = *(const bf16x8*)(wp + ks * 32);
            acc[nt] = __builtin_amdgcn_mfma_f32_16x16x32_bf16(a[ks], b, acc[nt], 0, 0, 0);
        }
    }

    int c  = lane & 15;
    int r0 = blockIdx.x * 64 + w * 16 + (lane >> 4) * 4;
    #pragma unroll
    for (int j = 0; j < 4; ++j) {
        int r = r0 + j;
        if (r < M) {
            #pragma unroll
            for (int nt = 0; nt < NT; ++nt)
                Y[(size_t)r * N + nt * 16 + c] = (ushort)f2bf(acc[nt][j]);
        }
    }
}

// ---------------- Aggregation ----------------
// Quarter split: q = blockIdx&3 (XCD i sees only quarter i%4 under the
// blockIdx%8 round-robin) -> per-XCD gather footprint 3.2 MB < 4 MB L2.
// Wave = one node: 16 feature-lanes x 4 edge-groups; shfl_xor(16,32) reduce.

template <bool RELU>
__global__ __launch_bounds__(256) void k_agg128(const unsigned* __restrict__ Y32, const int* __restrict__ offs,
                                                const ushort* __restrict__ esrc, const float* __restrict__ bias,
                                                unsigned* __restrict__ Z32, int n) {
    int wv   = threadIdx.x >> 6;
    int lane = threadIdx.x & 63;
    int l16  = lane & 15;
    int eg   = lane >> 4;             // edge sub-group 0..3
    int q    = blockIdx.x & 3;        // feature quarter (XCD-pinned)
    int v    = (blockIdx.x >> 2) * 4 + wv;
    if (v >= n) return;
    const unsigned* Yc = Y32 + q * 16 + l16;   // row stride 64 uints
    int start = offs[v], end = offs[v + 1];
    float scale = 1.0f / (float)(end - start + 2);
    float ax = 0.f, ay = 0.f;

    int e = start + eg;
    for (; e + 4 < end; e += 8) {          // two 4-edge slots in flight
        int s0 = esrc[e];
        int s1 = esrc[e + 4];
        unsigned t0 = Yc[(size_t)s0 * 64];
        unsigned t1 = Yc[(size_t)s1 * 64];
        ax += bflo(t0) + bflo(t1);
        ay += bfhi(t0) + bfhi(t1);
    }
    if (e < end) {
        unsigned t0 = Yc[(size_t)esrc[e] * 64];
        ax += bflo(t0);
        ay += bfhi(t0);
    }
    ax += __shfl_xor(ax, 16); ax += __shfl_xor(ax, 32);
    ay += __shfl_xor(ay, 16); ay += __shfl_xor(ay, 32);

    unsigned sf = Yc[(size_t)v * 64];
    float2 bb = ((const float2*)bias)[q * 16 + l16];
    float rx = (ax + 2.f * bflo(sf)) * scale + bb.x;
    float ry = (ay + 2.f * bfhi(sf)) * scale + bb.y;
    if (RELU) { rx = fmaxf(rx, 0.f); ry = fmaxf(ry, 0.f); }
    if (lane < 16)
        Z32[(size_t)v * 64 + q * 16 + l16] = (unsigned)f2bf(rx) | ((unsigned)f2bf(ry) << 16);
}

// 64-wide: half split (64B chunks), fp32 float2 output.
__global__ __launch_bounds__(256) void k_agg64(const unsigned* __restrict__ Y32, const int* __restrict__ offs,
                                               const ushort* __restrict__ esrc, const float* __restrict__ bias,
                                               float* __restrict__ Z, int n) {
    int wv   = threadIdx.x >> 6;
    int lane = threadIdx.x & 63;
    int l16  = lane & 15;
    int eg   = lane >> 4;
    int h    = blockIdx.x & 1;        // feature half (XCD parity)
    int v    = (blockIdx.x >> 1) * 4 + wv;
    if (v >= n) return;
    const unsigned* Yc = Y32 + h * 16 + l16;   // row stride 32 uints
    int start = offs[v], end = offs[v + 1];
    float scale = 1.0f / (float)(end - start + 2);
    float ax = 0.f, ay = 0.f;

    int e = start + eg;
    for (; e + 4 < end; e += 8) {
        int s0 = esrc[e];
        int s1 = esrc[e + 4];
        unsigned t0 = Yc[(size_t)s0 * 32];
        unsigned t1 = Yc[(size_t)s1 * 32];
        ax += bflo(t0) + bflo(t1);
        ay += bfhi(t0) + bfhi(t1);
    }
    if (e < end) {
        unsigned t0 = Yc[(size_t)esrc[e] * 32];
        ax += bflo(t0);
        ay += bfhi(t0);
    }
    ax += __shfl_xor(ax, 16); ax += __shfl_xor(ax, 32);
    ay += __shfl_xor(ay, 16); ay += __shfl_xor(ay, 32);

    unsigned sf = Yc[(size_t)v * 32];
    float2 bb = ((const float2*)bias)[h * 16 + l16];
    float rx = (ax + 2.f * bflo(sf)) * scale + bb.x;
    float ry = (ay + 2.f * bfhi(sf)) * scale + bb.y;
    if (lane < 16)
        *(float2*)&Z[(size_t)v * 64 + h * 32 + l16 * 2] = make_float2(rx, ry);
}

// ---------------- launch ----------------

extern "C" void kernel_launch(void* const* d_in, const int* in_sizes, int n_in,
                              void* d_out, int out_size, void* d_ws, size_t ws_size,
                              hipStream_t stream) {
    const float* in_feat = (const float*)d_in[0];
    const int*   src     = (const int*)d_in[1];
    const int*   dst     = (const int*)d_in[2];
    const float* W0      = (const float*)d_in[3];
    const float* b0      = (const float*)d_in[4];
    const float* W1      = (const float*)d_in[5];
    const float* b1      = (const float*)d_in[6];
    const float* W2      = (const float*)d_in[7];
    const float* b2      = (const float*)d_in[8];
    float* out = (float*)d_out;

    const int n  = in_sizes[0] / NFEAT;   // 50000 (<= 65536 assumed)
    const int ne = in_sizes[1];           // 800000
    const int nch = (n + 1023) / 1024;
    const int NB  = (n + 511) >> 9;       // buckets of 512 nodes

    // workspace carve (16B aligned)
    int* offs       = (int*)d_ws;                          // n+1
    int* tots       = offs + (((n + 1) + 3) & ~3);         // 1024
    int* gcur       = tots + 1024;                         // 128
    int* cnt        = gcur + 128;                          // n
    unsigned* pairs = (unsigned*)(cnt + ((n + 3) & ~3));   // 128*BKT_CAP
    ushort* esrc    = (ushort*)(pairs + (size_t)128 * BKT_CAP);  // ne (ushort)
    ushort* Wb      = esrc + ((ne + 7) & ~7);              // 40960
    ushort* Ybuf    = Wb + 40960;                          // n*128
    ushort* Zbuf    = Ybuf + (size_t)n * NFEAT;            // n*128

    // --- CSR build ---
    k_zero128<<<1, 128, 0, stream>>>(gcur);
    k_bin<<<(ne + 4095) / 4096, 256, 0, stream>>>(src, dst, gcur, pairs, ne);
    k_cnt<<<NB, 256, 0, stream>>>(pairs, gcur, cnt, n);
    k_scan_part<<<nch, 1024, 0, stream>>>(cnt, offs, tots, n);
    k_scan_tops<<<1, 1024, 0, stream>>>(tots, offs + n, nch);
    k_scan_add<<<nch, 1024, 0, stream>>>(offs, tots, n);
    k_scatter<<<NB, 256, 0, stream>>>(pairs, gcur, offs, esrc, n);

    // --- weights -> bf16 ---
    k_cast3<<<(40960 + 255) / 256, 256, 0, stream>>>(W0, 16384, W1, 16384, W2, 8192, Wb);
    const ushort* Wb0 = Wb;
    const ushort* Wb1 = Wb + 16384;
    const ushort* Wb2 = Wb + 32768;

    const int gg  = (n + 63) / 64;            // GEMM blocks
    const int nb4 = (n + 3) / 4;              // node-blocks (4 nodes/block)

    // --- layer 0 ---
    k_gemm_mfma<float, 128><<<gg, 256, 0, stream>>>(in_feat, Wb0, Ybuf, n);
    k_agg128<true><<<4 * nb4, 256, 0, stream>>>((const unsigned*)Ybuf, offs, esrc, b0, (unsigned*)Zbuf, n);

    // --- layer 1 ---
    k_gemm_mfma<ushort, 128><<<gg, 256, 0, stream>>>(Zbuf, Wb1, Ybuf, n);
    k_agg128<true><<<4 * nb4, 256, 0, stream>>>((const unsigned*)Ybuf, offs, esrc, b1, (unsigned*)Zbuf, n);

    // --- layer 2 (N=64, no relu, fp32 out) ---
    k_gemm_mfma<ushort, 64><<<gg, 256, 0, stream>>>(Zbuf, Wb2, Ybuf, n);
    k_agg64<<<2 * nb4, 256, 0, stream>>>((const unsigned*)Ybuf, offs, esrc, b2, out, n);

    (void)ws_size; (void)n_in; (void)out_size;
}

// Round 6
// 318.982 us; speedup vs baseline: 1.0303x; 1.0303x over previous
//
#include <hip/hip_runtime.h>
#include <hip/hip_bf16.h>

// ---------------------------------------------------------------------------
// SAGE-GCN x3 on MI355X.  Round 6.
//   CSR build: bucketed 2-pass (round 4).
//   Agg: feature-quarter split with REAL XCD residency: blocks read their
//     physical XCD id (s_getreg HW_REG_XCC_ID, m09-verified) and claim
//     16-node chunks from per-quarter atomic queues (preferred q = xcc&3,
//     steal-fallback for correctness).  Y/Z stored PLANE-MAJOR [4][n][32f]
//     so a quarter is one contiguous 3.2 MB region < 4 MB per-XCD L2.
//     Round-5 evidence: blockIdx&3 pinning gave 0% L2 hit (FETCH = 205 MB =
//     exactly 800k x 256 B) -> block->XCD mapping is not %8 round-robin.
//   GEMM: MFMA 16x16x32 bf16, reads/writes planes.
// ---------------------------------------------------------------------------

#define NFEAT 128
#define BKT_CAP 12288

using bf16x8 = __attribute__((ext_vector_type(8))) short;
using f32x4  = __attribute__((ext_vector_type(4))) float;

__device__ __forceinline__ ushort f2bf(float f) {
    unsigned u = __float_as_uint(f);
    u = (u + 0x7fffu + ((u >> 16) & 1u)) >> 16;
    return (ushort)u;
}
__device__ __forceinline__ float bflo(unsigned v) { return __uint_as_float(v << 16); }
__device__ __forceinline__ float bfhi(unsigned v) { return __uint_as_float(v & 0xffff0000u); }

__device__ __forceinline__ int xcc_id() {
    int x;
    asm volatile("s_getreg_b32 %0, hwreg(HW_REG_XCC_ID)" : "=s"(x));
    return x & 7;
}

// ---------------- CSR build ----------------

__global__ __launch_bounds__(512) void k_zero_words(int* __restrict__ p, int n) {
    int i = threadIdx.x;
    if (i < n) p[i] = 0;
}

__global__ __launch_bounds__(256) void k_bin(const int* __restrict__ src, const int* __restrict__ dst,
                                             int* __restrict__ gcur, unsigned* __restrict__ pairs, int ne) {
    __shared__ int lcnt[128];
    __shared__ int lbase[128];
    int tid = threadIdx.x;
    if (tid < 128) lcnt[tid] = 0;
    __syncthreads();
    int e0 = blockIdx.x * 4096;
    int myrank[16];
    int mybkt[16];
    unsigned mypair[16];
    #pragma unroll
    for (int i = 0; i < 16; ++i) {
        int e = e0 + tid + i * 256;
        if (e < ne) {
            int s = src[e], d = dst[e];
            int b = d >> 9;
            mybkt[i]  = b;
            mypair[i] = (unsigned)(s & 0xffff) | ((unsigned)(d & 511) << 16);
            myrank[i] = atomicAdd(&lcnt[b], 1);
        } else mybkt[i] = -1;
    }
    __syncthreads();
    if (tid < 128) lbase[tid] = lcnt[tid] ? atomicAdd(&gcur[tid], lcnt[tid]) : 0;
    __syncthreads();
    #pragma unroll
    for (int i = 0; i < 16; ++i) {
        if (mybkt[i] >= 0) {
            int pos = lbase[mybkt[i]] + myrank[i];
            if (pos < BKT_CAP) pairs[(size_t)mybkt[i] * BKT_CAP + pos] = mypair[i];
        }
    }
}

__global__ __launch_bounds__(256) void k_cnt(const unsigned* __restrict__ pairs, const int* __restrict__ gcur,
                                             int* __restrict__ cnt, int n) {
    __shared__ int lcnt[512];
    int b = blockIdx.x, tid = threadIdx.x;
    for (int i = tid; i < 512; i += 256) lcnt[i] = 0;
    __syncthreads();
    int m = gcur[b];
    if (m > BKT_CAP) m = BKT_CAP;
    const unsigned* p = pairs + (size_t)b * BKT_CAP;
    for (int i = tid; i < m; i += 256) atomicAdd(&lcnt[p[i] >> 16], 1);
    __syncthreads();
    int base = b * 512;
    for (int i = tid; i < 512; i += 256) {
        int node = base + i;
        if (node < n) cnt[node] = lcnt[i];
    }
}

__global__ __launch_bounds__(1024) void k_scan_part(const int* __restrict__ cnt, int* __restrict__ part,
                                                    int* __restrict__ tots, int n) {
    __shared__ int wtot[16];
    __shared__ int wpre[16];
    int tid  = threadIdx.x;
    int lane = tid & 63;
    int wv   = tid >> 6;
    int i    = blockIdx.x * 1024 + tid;
    int v    = (i < n) ? cnt[i] : 0;
    int val  = v;
    #pragma unroll
    for (int off = 1; off < 64; off <<= 1) {
        int t = __shfl_up(val, off);
        if (lane >= off) val += t;
    }
    if (lane == 63) wtot[wv] = val;
    __syncthreads();
    if (tid == 0) {
        int s = 0;
        #pragma unroll
        for (int w = 0; w < 16; ++w) { wpre[w] = s; s += wtot[w]; }
        tots[blockIdx.x] = s;
    }
    __syncthreads();
    int excl = val - v + wpre[wv];
    if (i < n) part[i] = excl;
}

__global__ __launch_bounds__(1024) void k_scan_tops(int* __restrict__ tots, int* __restrict__ total_out, int nch) {
    __shared__ int wtot[16];
    __shared__ int wpre[16];
    int tid  = threadIdx.x;
    int lane = tid & 63;
    int wv   = tid >> 6;
    int v    = (tid < nch) ? tots[tid] : 0;
    int val  = v;
    #pragma unroll
    for (int off = 1; off < 64; off <<= 1) {
        int t = __shfl_up(val, off);
        if (lane >= off) val += t;
    }
    if (lane == 63) wtot[wv] = val;
    __syncthreads();
    if (tid == 0) {
        int s = 0;
        #pragma unroll
        for (int w = 0; w < 16; ++w) { wpre[w] = s; s += wtot[w]; }
        *total_out = s;
    }
    __syncthreads();
    int excl = val - v + wpre[wv];
    if (tid < nch) tots[tid] = excl;
}

__global__ __launch_bounds__(1024) void k_scan_add(int* __restrict__ offs, const int* __restrict__ tots, int n) {
    int i = blockIdx.x * 1024 + threadIdx.x;
    if (i < n) offs[i] += tots[blockIdx.x];
}

__global__ __launch_bounds__(256) void k_scatter(const unsigned* __restrict__ pairs, const int* __restrict__ gcur,
                                                 const int* __restrict__ offs, ushort* __restrict__ esrc, int n) {
    __shared__ int lcur[512];
    __shared__ int loffs[512];
    int b = blockIdx.x, tid = threadIdx.x;
    int base = b * 512;
    for (int i = tid; i < 512; i += 256) {
        lcur[i] = 0;
        int node = base + i;
        loffs[i] = (node < n) ? offs[node] : 0;
    }
    __syncthreads();
    int m = gcur[b];
    if (m > BKT_CAP) m = BKT_CAP;
    const unsigned* p = pairs + (size_t)b * BKT_CAP;
    for (int i = tid; i < m; i += 256) {
        unsigned pr = p[i];
        int dlow = pr >> 16;
        int r = atomicAdd(&lcur[dlow], 1);
        esrc[loffs[dlow] + r] = (ushort)(pr & 0xffffu);
    }
}

// ---------------- cast W0|W1|W2 -> bf16 ----------------

__global__ __launch_bounds__(256) void k_cast3(const float* __restrict__ a, int na,
                                               const float* __restrict__ b, int nb,
                                               const float* __restrict__ c, int nc,
                                               ushort* __restrict__ out) {
    int i = blockIdx.x * 256 + threadIdx.x;
    if (i >= na + nb + nc) return;
    float v = (i < na) ? a[i] : ((i < na + nb) ? b[i - na] : c[i - na - nb]);
    out[i] = f2bf(v);
}

// ---------------- GEMM: planes_out[N/32][M][32] = X @ Wb^T ----------------
// PLANES_IN: X is bf16 plane-major [4][M][32]; else canonical fp32 [M][128].

template <typename InT, int N, bool PLANES_IN>
__global__ __launch_bounds__(256) void k_gemm_mfma(const InT* __restrict__ X, const ushort* __restrict__ Wb,
                                                   ushort* __restrict__ Y, int M) {
    int w    = threadIdx.x >> 6;
    int lane = threadIdx.x & 63;
    int rowf = blockIdx.x * 64 + w * 16 + (lane & 15);
    int kb   = (lane >> 4) * 8;

    bf16x8 a[4];
    if (rowf < M) {
        #pragma unroll
        for (int ks = 0; ks < 4; ++ks) {
            if constexpr (PLANES_IN) {
                a[ks] = *(const bf16x8*)((const ushort*)X + (size_t)ks * M * 32 + (size_t)rowf * 32 + kb);
            } else {
                const float* xp = (const float*)X + (size_t)rowf * 128 + ks * 32 + kb;
                float4 f0 = *(const float4*)xp;
                float4 f1 = *(const float4*)(xp + 4);
                bf16x8 t;
                t[0] = f2bf(f0.x); t[1] = f2bf(f0.y); t[2] = f2bf(f0.z); t[3] = f2bf(f0.w);
                t[4] = f2bf(f1.x); t[5] = f2bf(f1.y); t[6] = f2bf(f1.z); t[7] = f2bf(f1.w);
                a[ks] = t;
            }
        }
    } else {
        #pragma unroll
        for (int ks = 0; ks < 4; ++ks) {
            bf16x8 z = {0, 0, 0, 0, 0, 0, 0, 0};
            a[ks] = z;
        }
    }

    constexpr int NT = N / 16;
    f32x4 acc[NT];
    #pragma unroll
    for (int nt = 0; nt < NT; ++nt) acc[nt] = (f32x4){0.f, 0.f, 0.f, 0.f};

    #pragma unroll
    for (int nt = 0; nt < NT; ++nt) {
        const ushort* wp = Wb + (size_t)(nt * 16 + (lane & 15)) * 128 + kb;
        #pragma unroll
        for (int ks = 0; ks < 4; ++ks) {
            bf16x8 b = *(const bf16x8*)(wp + ks * 32);
            acc[nt] = __builtin_amdgcn_mfma_f32_16x16x32_bf16(a[ks], b, acc[nt], 0, 0, 0);
        }
    }

    // plane-major store: feature f = nt*16+c -> plane nt>>1, in-row (nt&1)*16+c
    int c  = lane & 15;
    int r0 = blockIdx.x * 64 + w * 16 + (lane >> 4) * 4;
    #pragma unroll
    for (int j = 0; j < 4; ++j) {
        int r = r0 + j;
        if (r < M) {
            #pragma unroll
            for (int nt = 0; nt < NT; ++nt)
                Y[(size_t)(nt >> 1) * M * 32 + (size_t)r * 32 + (nt & 1) * 16 + c] = (ushort)f2bf(acc[nt][j]);
        }
    }
}

// ---------------- Aggregation (XCC-scheduled quarter/half planes) ----------------
// Each block claims one 16-node chunk for its preferred feature-plane set.
// Wave = one node at a time: 16 feature-lanes x 4 edge-groups, shfl reduce.

template <bool RELU>
__global__ __launch_bounds__(256) void k_agg128(const unsigned* __restrict__ Yp, const int* __restrict__ offs,
                                                const ushort* __restrict__ esrc, const float* __restrict__ bias,
                                                unsigned* __restrict__ Zp, int* __restrict__ qh,
                                                int n, int nchunk) {
    __shared__ int sQ, sT;
    if (threadIdx.x == 0) {
        int pref = xcc_id() & 3;
        int t = -1, qsel = 0;
        #pragma unroll
        for (int a = 0; a < 4; ++a) {
            int cand = (pref + a) & 3;
            int tt = atomicAdd(&qh[cand * 16], 1);
            if (tt < nchunk) { qsel = cand; t = tt; break; }
        }
        sQ = qsel; sT = t;
    }
    __syncthreads();
    int q = sQ, t = sT;
    if (t < 0) return;
    int wv   = threadIdx.x >> 6;
    int lane = threadIdx.x & 63;
    int l16  = lane & 15;
    int eg   = lane >> 4;
    const unsigned* Yq = Yp + (size_t)q * n * 16;
    unsigned*       Zq = Zp + (size_t)q * n * 16;
    float2 bb = ((const float2*)bias)[q * 16 + l16];

    #pragma unroll
    for (int i = 0; i < 4; ++i) {
        int v = t * 16 + wv + i * 4;
        if (v >= n) break;
        int start = offs[v], end = offs[v + 1];
        float scale = 1.0f / (float)(end - start + 2);
        float ax = 0.f, ay = 0.f;
        int e = start + eg;
        for (; e + 4 < end; e += 8) {
            unsigned t0 = Yq[(size_t)esrc[e] * 16 + l16];
            unsigned t1 = Yq[(size_t)esrc[e + 4] * 16 + l16];
            ax += bflo(t0) + bflo(t1);
            ay += bfhi(t0) + bfhi(t1);
        }
        if (e < end) {
            unsigned t0 = Yq[(size_t)esrc[e] * 16 + l16];
            ax += bflo(t0);
            ay += bfhi(t0);
        }
        ax += __shfl_xor(ax, 16); ax += __shfl_xor(ax, 32);
        ay += __shfl_xor(ay, 16); ay += __shfl_xor(ay, 32);
        unsigned sf = Yq[(size_t)v * 16 + l16];
        float rx = (ax + 2.f * bflo(sf)) * scale + bb.x;
        float ry = (ay + 2.f * bfhi(sf)) * scale + bb.y;
        if (RELU) { rx = fmaxf(rx, 0.f); ry = fmaxf(ry, 0.f); }
        if (lane < 16)
            Zq[(size_t)v * 16 + l16] = (unsigned)f2bf(rx) | ((unsigned)f2bf(ry) << 16);
    }
}

// Layer-2: 64 feats in 2 planes [2][n][32f]; canonical fp32 [n][64] output.
__global__ __launch_bounds__(256) void k_agg64(const unsigned* __restrict__ Yp, const int* __restrict__ offs,
                                               const ushort* __restrict__ esrc, const float* __restrict__ bias,
                                               float* __restrict__ Z, int* __restrict__ qh,
                                               int n, int nchunk) {
    __shared__ int sQ, sT;
    if (threadIdx.x == 0) {
        int pref = xcc_id() & 1;
        int t = -1, qsel = 0;
        #pragma unroll
        for (int a = 0; a < 2; ++a) {
            int cand = (pref + a) & 1;
            int tt = atomicAdd(&qh[cand * 16], 1);
            if (tt < nchunk) { qsel = cand; t = tt; break; }
        }
        sQ = qsel; sT = t;
    }
    __syncthreads();
    int h = sQ, t = sT;
    if (t < 0) return;
    int wv   = threadIdx.x >> 6;
    int lane = threadIdx.x & 63;
    int l16  = lane & 15;
    int eg   = lane >> 4;
    const unsigned* Yh = Yp + (size_t)h * n * 16;
    float2 bb = ((const float2*)bias)[h * 16 + l16];

    #pragma unroll
    for (int i = 0; i < 4; ++i) {
        int v = t * 16 + wv + i * 4;
        if (v >= n) break;
        int start = offs[v], end = offs[v + 1];
        float scale = 1.0f / (float)(end - start + 2);
        float ax = 0.f, ay = 0.f;
        int e = start + eg;
        for (; e + 4 < end; e += 8) {
            unsigned t0 = Yh[(size_t)esrc[e] * 16 + l16];
            unsigned t1 = Yh[(size_t)esrc[e + 4] * 16 + l16];
            ax += bflo(t0) + bflo(t1);
            ay += bfhi(t0) + bfhi(t1);
        }
        if (e < end) {
            unsigned t0 = Yh[(size_t)esrc[e] * 16 + l16];
            ax += bflo(t0);
            ay += bfhi(t0);
        }
        ax += __shfl_xor(ax, 16); ax += __shfl_xor(ax, 32);
        ay += __shfl_xor(ay, 16); ay += __shfl_xor(ay, 32);
        unsigned sf = Yh[(size_t)v * 16 + l16];
        float rx = (ax + 2.f * bflo(sf)) * scale + bb.x;
        float ry = (ay + 2.f * bfhi(sf)) * scale + bb.y;
        if (lane < 16)
            *(float2*)&Z[(size_t)v * 64 + h * 32 + l16 * 2] = make_float2(rx, ry);
    }
}

// ---------------- launch ----------------

extern "C" void kernel_launch(void* const* d_in, const int* in_sizes, int n_in,
                              void* d_out, int out_size, void* d_ws, size_t ws_size,
                              hipStream_t stream) {
    const float* in_feat = (const float*)d_in[0];
    const int*   src     = (const int*)d_in[1];
    const int*   dst     = (const int*)d_in[2];
    const float* W0      = (const float*)d_in[3];
    const float* b0      = (const float*)d_in[4];
    const float* W1      = (const float*)d_in[5];
    const float* b1      = (const float*)d_in[6];
    const float* W2      = (const float*)d_in[7];
    const float* b2      = (const float*)d_in[8];
    float* out = (float*)d_out;

    const int n  = in_sizes[0] / NFEAT;   // 50000 (<= 65536 assumed)
    const int ne = in_sizes[1];           // 800000
    const int nch = (n + 1023) / 1024;
    const int NB  = (n + 511) >> 9;
    const int nchunk = (n + 15) / 16;     // 16-node work chunks

    // workspace carve (16B aligned)
    int* offs       = (int*)d_ws;                          // n+1
    int* tots       = offs + (((n + 1) + 3) & ~3);         // 1024
    int* gcur       = tots + 1024;                         // 128
    int* qh         = gcur + 128;                          // 3*64 (claim counters)
    int* cnt        = qh + 192;                            // n
    unsigned* pairs = (unsigned*)(cnt + ((n + 3) & ~3));   // 128*BKT_CAP
    ushort* esrc    = (ushort*)(pairs + (size_t)128 * BKT_CAP);  // ne
    ushort* Wb      = esrc + ((ne + 7) & ~7);              // 40960
    ushort* Ybuf    = Wb + 40960;                          // n*128 (plane-major)
    ushort* Zbuf    = Ybuf + (size_t)n * NFEAT;            // n*128 (plane-major)

    // --- CSR build ---
    k_zero_words<<<1, 512, 0, stream>>>(gcur, 128 + 192);
    k_bin<<<(ne + 4095) / 4096, 256, 0, stream>>>(src, dst, gcur, pairs, ne);
    k_cnt<<<NB, 256, 0, stream>>>(pairs, gcur, cnt, n);
    k_scan_part<<<nch, 1024, 0, stream>>>(cnt, offs, tots, n);
    k_scan_tops<<<1, 1024, 0, stream>>>(tots, offs + n, nch);
    k_scan_add<<<nch, 1024, 0, stream>>>(offs, tots, n);
    k_scatter<<<NB, 256, 0, stream>>>(pairs, gcur, offs, esrc, n);

    // --- weights -> bf16 ---
    k_cast3<<<(40960 + 255) / 256, 256, 0, stream>>>(W0, 16384, W1, 16384, W2, 8192, Wb);
    const ushort* Wb0 = Wb;
    const ushort* Wb1 = Wb + 16384;
    const ushort* Wb2 = Wb + 32768;

    const int gg = (n + 63) / 64;

    // --- layer 0 ---
    k_gemm_mfma<float, 128, false><<<gg, 256, 0, stream>>>(in_feat, Wb0, Ybuf, n);
    k_agg128<true><<<4 * nchunk, 256, 0, stream>>>((const unsigned*)Ybuf, offs, esrc, b0,
                                                   (unsigned*)Zbuf, qh, n, nchunk);
    // --- layer 1 ---
    k_gemm_mfma<ushort, 128, true><<<gg, 256, 0, stream>>>(Zbuf, Wb1, Ybuf, n);
    k_agg128<true><<<4 * nchunk, 256, 0, stream>>>((const unsigned*)Ybuf, offs, esrc, b1,
                                                   (unsigned*)Zbuf, qh + 64, n, nchunk);
    // --- layer 2 (N=64, no relu, fp32 out) ---
    k_gemm_mfma<ushort, 64, true><<<gg, 256, 0, stream>>>(Zbuf, Wb2, Ybuf, n);
    k_agg64<<<2 * nchunk, 256, 0, stream>>>((const unsigned*)Ybuf, offs, esrc, b2,
                                            out, qh + 128, n, nchunk);

    (void)ws_size; (void)n_in; (void)out_size;
}

// Round 7
// 308.424 us; speedup vs baseline: 1.0656x; 1.0342x over previous
//
#include <hip/hip_runtime.h>
#include <hip/hip_bf16.h>

// ---------------------------------------------------------------------------
// SAGE-GCN x3 on MI355X.  Round 7.
//   Agg: XCC-resident quarter planes (round 6: FETCH 205->17 MB, proven) with
//     execution-structure fixes: 64-node chunks (4x fewer claim atomics),
//     4-deep edge unroll (16 gathers in flight/wave), clamped node loop.
//   CSR build: bucketed 2-pass (round 4).
//   GEMM: MFMA 16x16x32 bf16, plane-major I/O.
// ---------------------------------------------------------------------------

#define NFEAT 128
#define BKT_CAP 12288
#define CHUNK 64

using bf16x8 = __attribute__((ext_vector_type(8))) short;
using f32x4  = __attribute__((ext_vector_type(4))) float;

__device__ __forceinline__ ushort f2bf(float f) {
    unsigned u = __float_as_uint(f);
    u = (u + 0x7fffu + ((u >> 16) & 1u)) >> 16;
    return (ushort)u;
}
__device__ __forceinline__ float bflo(unsigned v) { return __uint_as_float(v << 16); }
__device__ __forceinline__ float bfhi(unsigned v) { return __uint_as_float(v & 0xffff0000u); }

__device__ __forceinline__ int xcc_id() {
    int x;
    asm volatile("s_getreg_b32 %0, hwreg(HW_REG_XCC_ID)" : "=s"(x));
    return x & 7;
}

// ---------------- CSR build ----------------

__global__ __launch_bounds__(512) void k_zero_words(int* __restrict__ p, int n) {
    int i = threadIdx.x;
    if (i < n) p[i] = 0;
}

__global__ __launch_bounds__(256) void k_bin(const int* __restrict__ src, const int* __restrict__ dst,
                                             int* __restrict__ gcur, unsigned* __restrict__ pairs, int ne) {
    __shared__ int lcnt[128];
    __shared__ int lbase[128];
    int tid = threadIdx.x;
    if (tid < 128) lcnt[tid] = 0;
    __syncthreads();
    int e0 = blockIdx.x * 4096;
    int myrank[16];
    int mybkt[16];
    unsigned mypair[16];
    #pragma unroll
    for (int i = 0; i < 16; ++i) {
        int e = e0 + tid + i * 256;
        if (e < ne) {
            int s = src[e], d = dst[e];
            int b = d >> 9;
            mybkt[i]  = b;
            mypair[i] = (unsigned)(s & 0xffff) | ((unsigned)(d & 511) << 16);
            myrank[i] = atomicAdd(&lcnt[b], 1);
        } else mybkt[i] = -1;
    }
    __syncthreads();
    if (tid < 128) lbase[tid] = lcnt[tid] ? atomicAdd(&gcur[tid], lcnt[tid]) : 0;
    __syncthreads();
    #pragma unroll
    for (int i = 0; i < 16; ++i) {
        if (mybkt[i] >= 0) {
            int pos = lbase[mybkt[i]] + myrank[i];
            if (pos < BKT_CAP) pairs[(size_t)mybkt[i] * BKT_CAP + pos] = mypair[i];
        }
    }
}

__global__ __launch_bounds__(256) void k_cnt(const unsigned* __restrict__ pairs, const int* __restrict__ gcur,
                                             int* __restrict__ cnt, int n) {
    __shared__ int lcnt[512];
    int b = blockIdx.x, tid = threadIdx.x;
    for (int i = tid; i < 512; i += 256) lcnt[i] = 0;
    __syncthreads();
    int m = gcur[b];
    if (m > BKT_CAP) m = BKT_CAP;
    const unsigned* p = pairs + (size_t)b * BKT_CAP;
    for (int i = tid; i < m; i += 256) atomicAdd(&lcnt[p[i] >> 16], 1);
    __syncthreads();
    int base = b * 512;
    for (int i = tid; i < 512; i += 256) {
        int node = base + i;
        if (node < n) cnt[node] = lcnt[i];
    }
}

__global__ __launch_bounds__(1024) void k_scan_part(const int* __restrict__ cnt, int* __restrict__ part,
                                                    int* __restrict__ tots, int n) {
    __shared__ int wtot[16];
    __shared__ int wpre[16];
    int tid  = threadIdx.x;
    int lane = tid & 63;
    int wv   = tid >> 6;
    int i    = blockIdx.x * 1024 + tid;
    int v    = (i < n) ? cnt[i] : 0;
    int val  = v;
    #pragma unroll
    for (int off = 1; off < 64; off <<= 1) {
        int t = __shfl_up(val, off);
        if (lane >= off) val += t;
    }
    if (lane == 63) wtot[wv] = val;
    __syncthreads();
    if (tid == 0) {
        int s = 0;
        #pragma unroll
        for (int w = 0; w < 16; ++w) { wpre[w] = s; s += wtot[w]; }
        tots[blockIdx.x] = s;
    }
    __syncthreads();
    int excl = val - v + wpre[wv];
    if (i < n) part[i] = excl;
}

__global__ __launch_bounds__(1024) void k_scan_tops(int* __restrict__ tots, int* __restrict__ total_out, int nch) {
    __shared__ int wtot[16];
    __shared__ int wpre[16];
    int tid  = threadIdx.x;
    int lane = tid & 63;
    int wv   = tid >> 6;
    int v    = (tid < nch) ? tots[tid] : 0;
    int val  = v;
    #pragma unroll
    for (int off = 1; off < 64; off <<= 1) {
        int t = __shfl_up(val, off);
        if (lane >= off) val += t;
    }
    if (lane == 63) wtot[wv] = val;
    __syncthreads();
    if (tid == 0) {
        int s = 0;
        #pragma unroll
        for (int w = 0; w < 16; ++w) { wpre[w] = s; s += wtot[w]; }
        *total_out = s;
    }
    __syncthreads();
    int excl = val - v + wpre[wv];
    if (tid < nch) tots[tid] = excl;
}

__global__ __launch_bounds__(1024) void k_scan_add(int* __restrict__ offs, const int* __restrict__ tots, int n) {
    int i = blockIdx.x * 1024 + threadIdx.x;
    if (i < n) offs[i] += tots[blockIdx.x];
}

__global__ __launch_bounds__(256) void k_scatter(const unsigned* __restrict__ pairs, const int* __restrict__ gcur,
                                                 const int* __restrict__ offs, ushort* __restrict__ esrc, int n) {
    __shared__ int lcur[512];
    __shared__ int loffs[512];
    int b = blockIdx.x, tid = threadIdx.x;
    int base = b * 512;
    for (int i = tid; i < 512; i += 256) {
        lcur[i] = 0;
        int node = base + i;
        loffs[i] = (node < n) ? offs[node] : 0;
    }
    __syncthreads();
    int m = gcur[b];
    if (m > BKT_CAP) m = BKT_CAP;
    const unsigned* p = pairs + (size_t)b * BKT_CAP;
    for (int i = tid; i < m; i += 256) {
        unsigned pr = p[i];
        int dlow = pr >> 16;
        int r = atomicAdd(&lcur[dlow], 1);
        esrc[loffs[dlow] + r] = (ushort)(pr & 0xffffu);
    }
}

// ---------------- cast W0|W1|W2 -> bf16 ----------------

__global__ __launch_bounds__(256) void k_cast3(const float* __restrict__ a, int na,
                                               const float* __restrict__ b, int nb,
                                               const float* __restrict__ c, int nc,
                                               ushort* __restrict__ out) {
    int i = blockIdx.x * 256 + threadIdx.x;
    if (i >= na + nb + nc) return;
    float v = (i < na) ? a[i] : ((i < na + nb) ? b[i - na] : c[i - na - nb]);
    out[i] = f2bf(v);
}

// ---------------- GEMM: planes_out[N/32][M][32] = X @ Wb^T ----------------

template <typename InT, int N, bool PLANES_IN>
__global__ __launch_bounds__(256) void k_gemm_mfma(const InT* __restrict__ X, const ushort* __restrict__ Wb,
                                                   ushort* __restrict__ Y, int M) {
    int w    = threadIdx.x >> 6;
    int lane = threadIdx.x & 63;
    int rowf = blockIdx.x * 64 + w * 16 + (lane & 15);
    int kb   = (lane >> 4) * 8;

    bf16x8 a[4];
    if (rowf < M) {
        #pragma unroll
        for (int ks = 0; ks < 4; ++ks) {
            if constexpr (PLANES_IN) {
                a[ks] = *(const bf16x8*)((const ushort*)X + (size_t)ks * M * 32 + (size_t)rowf * 32 + kb);
            } else {
                const float* xp = (const float*)X + (size_t)rowf * 128 + ks * 32 + kb;
                float4 f0 = *(const float4*)xp;
                float4 f1 = *(const float4*)(xp + 4);
                bf16x8 t;
                t[0] = f2bf(f0.x); t[1] = f2bf(f0.y); t[2] = f2bf(f0.z); t[3] = f2bf(f0.w);
                t[4] = f2bf(f1.x); t[5] = f2bf(f1.y); t[6] = f2bf(f1.z); t[7] = f2bf(f1.w);
                a[ks] = t;
            }
        }
    } else {
        #pragma unroll
        for (int ks = 0; ks < 4; ++ks) {
            bf16x8 z = {0, 0, 0, 0, 0, 0, 0, 0};
            a[ks] = z;
        }
    }

    constexpr int NT = N / 16;
    f32x4 acc[NT];
    #pragma unroll
    for (int nt = 0; nt < NT; ++nt) acc[nt] = (f32x4){0.f, 0.f, 0.f, 0.f};

    #pragma unroll
    for (int nt = 0; nt < NT; ++nt) {
        const ushort* wp = Wb + (size_t)(nt * 16 + (lane & 15)) * 128 + kb;
        #pragma unroll
        for (int ks = 0; ks < 4; ++ks) {
            bf16x8 b = *(const bf16x8*)(wp + ks * 32);
            acc[nt] = __builtin_amdgcn_mfma_f32_16x16x32_bf16(a[ks], b, acc[nt], 0, 0, 0);
        }
    }

    int c  = lane & 15;
    int r0 = blockIdx.x * 64 + w * 16 + (lane >> 4) * 4;
    #pragma unroll
    for (int j = 0; j < 4; ++j) {
        int r = r0 + j;
        if (r < M) {
            #pragma unroll
            for (int nt = 0; nt < NT; ++nt)
                Y[(size_t)(nt >> 1) * M * 32 + (size_t)r * 32 + (nt & 1) * 16 + c] = (ushort)f2bf(acc[nt][j]);
        }
    }
}

// ---------------- Aggregation (XCC-scheduled planes, 64-node chunks) ----------------
// Wave = 16 nodes sequentially; per node: 16 feat-lanes x 4 edge-groups,
// 4-deep unroll (16 gathers in flight), shfl_xor(16,32) reduce.

template <bool RELU>
__global__ __launch_bounds__(256) void k_agg128(const unsigned* __restrict__ Yp, const int* __restrict__ offs,
                                                const ushort* __restrict__ esrc, const float* __restrict__ bias,
                                                unsigned* __restrict__ Zp, int* __restrict__ qh,
                                                int n, int nchunk) {
    __shared__ int sQ, sT;
    if (threadIdx.x == 0) {
        int pref = xcc_id() & 3;
        int t = -1, qsel = 0;
        #pragma unroll
        for (int a = 0; a < 4; ++a) {
            int cand = (pref + a) & 3;
            int tt = atomicAdd(&qh[cand * 16], 1);
            if (tt < nchunk) { qsel = cand; t = tt; break; }
        }
        sQ = qsel; sT = t;
    }
    __syncthreads();
    int q = sQ, t = sT;
    if (t < 0) return;
    int wv   = threadIdx.x >> 6;
    int lane = threadIdx.x & 63;
    int l16  = lane & 15;
    int eg   = lane >> 4;
    const unsigned* Yq = Yp + (size_t)q * n * 16 + l16;
    unsigned*       Zq = Zp + (size_t)q * n * 16;
    float2 bb = ((const float2*)bias)[q * 16 + l16];

    int v0   = t * CHUNK + wv * 16;
    int vend = v0 + 16 < n ? v0 + 16 : n;
    for (int v = v0; v < vend; ++v) {
        int start = offs[v], end = offs[v + 1];
        float scale = 1.0f / (float)(end - start + 2);
        float ax = 0.f, ay = 0.f;
        int e = start + eg;
        for (; e + 12 < end; e += 16) {   // 4-deep: 16 gathers in flight/wave
            unsigned t0 = Yq[(size_t)esrc[e] * 16];
            unsigned t1 = Yq[(size_t)esrc[e + 4] * 16];
            unsigned t2 = Yq[(size_t)esrc[e + 8] * 16];
            unsigned t3 = Yq[(size_t)esrc[e + 12] * 16];
            ax += bflo(t0) + bflo(t1) + bflo(t2) + bflo(t3);
            ay += bfhi(t0) + bfhi(t1) + bfhi(t2) + bfhi(t3);
        }
        for (; e < end; e += 4) {
            unsigned t0 = Yq[(size_t)esrc[e] * 16];
            ax += bflo(t0);
            ay += bfhi(t0);
        }
        ax += __shfl_xor(ax, 16); ax += __shfl_xor(ax, 32);
        ay += __shfl_xor(ay, 16); ay += __shfl_xor(ay, 32);
        unsigned sf = Yq[(size_t)v * 16];
        float rx = (ax + 2.f * bflo(sf)) * scale + bb.x;
        float ry = (ay + 2.f * bfhi(sf)) * scale + bb.y;
        if (RELU) { rx = fmaxf(rx, 0.f); ry = fmaxf(ry, 0.f); }
        if (lane < 16)
            Zq[(size_t)v * 16 + l16] = (unsigned)f2bf(rx) | ((unsigned)f2bf(ry) << 16);
    }
}

// Layer-2: 64 feats in 2 planes [2][n][32f]; canonical fp32 [n][64] output.
__global__ __launch_bounds__(256) void k_agg64(const unsigned* __restrict__ Yp, const int* __restrict__ offs,
                                               const ushort* __restrict__ esrc, const float* __restrict__ bias,
                                               float* __restrict__ Z, int* __restrict__ qh,
                                               int n, int nchunk) {
    __shared__ int sQ, sT;
    if (threadIdx.x == 0) {
        int pref = xcc_id() & 1;
        int t = -1, qsel = 0;
        #pragma unroll
        for (int a = 0; a < 2; ++a) {
            int cand = (pref + a) & 1;
            int tt = atomicAdd(&qh[cand * 16], 1);
            if (tt < nchunk) { qsel = cand; t = tt; break; }
        }
        sQ = qsel; sT = t;
    }
    __syncthreads();
    int h = sQ, t = sT;
    if (t < 0) return;
    int wv   = threadIdx.x >> 6;
    int lane = threadIdx.x & 63;
    int l16  = lane & 15;
    int eg   = lane >> 4;
    const unsigned* Yh = Yp + (size_t)h * n * 16 + l16;
    float2 bb = ((const float2*)bias)[h * 16 + l16];

    int v0   = t * CHUNK + wv * 16;
    int vend = v0 + 16 < n ? v0 + 16 : n;
    for (int v = v0; v < vend; ++v) {
        int start = offs[v], end = offs[v + 1];
        float scale = 1.0f / (float)(end - start + 2);
        float ax = 0.f, ay = 0.f;
        int e = start + eg;
        for (; e + 12 < end; e += 16) {
            unsigned t0 = Yh[(size_t)esrc[e] * 16];
            unsigned t1 = Yh[(size_t)esrc[e + 4] * 16];
            unsigned t2 = Yh[(size_t)esrc[e + 8] * 16];
            unsigned t3 = Yh[(size_t)esrc[e + 12] * 16];
            ax += bflo(t0) + bflo(t1) + bflo(t2) + bflo(t3);
            ay += bfhi(t0) + bfhi(t1) + bfhi(t2) + bfhi(t3);
        }
        for (; e < end; e += 4) {
            unsigned t0 = Yh[(size_t)esrc[e] * 16];
            ax += bflo(t0);
            ay += bfhi(t0);
        }
        ax += __shfl_xor(ax, 16); ax += __shfl_xor(ax, 32);
        ay += __shfl_xor(ay, 16); ay += __shfl_xor(ay, 32);
        unsigned sf = Yh[(size_t)v * 16];
        float rx = (ax + 2.f * bflo(sf)) * scale + bb.x;
        float ry = (ay + 2.f * bfhi(sf)) * scale + bb.y;
        if (lane < 16)
            *(float2*)&Z[(size_t)v * 64 + h * 32 + l16 * 2] = make_float2(rx, ry);
    }
}

// ---------------- launch ----------------

extern "C" void kernel_launch(void* const* d_in, const int* in_sizes, int n_in,
                              void* d_out, int out_size, void* d_ws, size_t ws_size,
                              hipStream_t stream) {
    const float* in_feat = (const float*)d_in[0];
    const int*   src     = (const int*)d_in[1];
    const int*   dst     = (const int*)d_in[2];
    const float* W0      = (const float*)d_in[3];
    const float* b0      = (const float*)d_in[4];
    const float* W1      = (const float*)d_in[5];
    const float* b1      = (const float*)d_in[6];
    const float* W2      = (const float*)d_in[7];
    const float* b2      = (const float*)d_in[8];
    float* out = (float*)d_out;

    const int n  = in_sizes[0] / NFEAT;   // 50000 (<= 65536 assumed)
    const int ne = in_sizes[1];           // 800000
    const int nch = (n + 1023) / 1024;
    const int NB  = (n + 511) >> 9;
    const int nchunk = (n + CHUNK - 1) / CHUNK;   // 64-node work chunks

    // workspace carve (16B aligned)
    int* offs       = (int*)d_ws;                          // n+1
    int* tots       = offs + (((n + 1) + 3) & ~3);         // 1024
    int* gcur       = tots + 1024;                         // 128
    int* qh         = gcur + 128;                          // 3*64 claim counters
    int* cnt        = qh + 192;                            // n
    unsigned* pairs = (unsigned*)(cnt + ((n + 3) & ~3));   // 128*BKT_CAP
    ushort* esrc    = (ushort*)(pairs + (size_t)128 * BKT_CAP);  // ne
    ushort* Wb      = esrc + ((ne + 7) & ~7);              // 40960
    ushort* Ybuf    = Wb + 40960;                          // n*128 (plane-major)
    ushort* Zbuf    = Ybuf + (size_t)n * NFEAT;            // n*128 (plane-major)

    // --- CSR build ---
    k_zero_words<<<1, 512, 0, stream>>>(gcur, 128 + 192);
    k_bin<<<(ne + 4095) / 4096, 256, 0, stream>>>(src, dst, gcur, pairs, ne);
    k_cnt<<<NB, 256, 0, stream>>>(pairs, gcur, cnt, n);
    k_scan_part<<<nch, 1024, 0, stream>>>(cnt, offs, tots, n);
    k_scan_tops<<<1, 1024, 0, stream>>>(tots, offs + n, nch);
    k_scan_add<<<nch, 1024, 0, stream>>>(offs, tots, n);
    k_scatter<<<NB, 256, 0, stream>>>(pairs, gcur, offs, esrc, n);

    // --- weights -> bf16 ---
    k_cast3<<<(40960 + 255) / 256, 256, 0, stream>>>(W0, 16384, W1, 16384, W2, 8192, Wb);
    const ushort* Wb0 = Wb;
    const ushort* Wb1 = Wb + 16384;
    const ushort* Wb2 = Wb + 32768;

    const int gg = (n + 63) / 64;

    // --- layer 0 ---
    k_gemm_mfma<float, 128, false><<<gg, 256, 0, stream>>>(in_feat, Wb0, Ybuf, n);
    k_agg128<true><<<4 * nchunk, 256, 0, stream>>>((const unsigned*)Ybuf, offs, esrc, b0,
                                                   (unsigned*)Zbuf, qh, n, nchunk);
    // --- layer 1 ---
    k_gemm_mfma<ushort, 128, true><<<gg, 256, 0, stream>>>(Zbuf, Wb1, Ybuf, n);
    k_agg128<true><<<4 * nchunk, 256, 0, stream>>>((const unsigned*)Ybuf, offs, esrc, b1,
                                                   (unsigned*)Zbuf, qh + 64, n, nchunk);
    // --- layer 2 (N=64, no relu, fp32 out) ---
    k_gemm_mfma<ushort, 64, true><<<gg, 256, 0, stream>>>(Zbuf, Wb2, Ybuf, n);
    k_agg64<<<2 * nchunk, 256, 0, stream>>>((const unsigned*)Ybuf, offs, esrc, b2,
                                            out, qh + 128, n, nchunk);

    (void)ws_size; (void)n_in; (void)out_size;
}

// Round 8
// 249.920 us; speedup vs baseline: 1.3150x; 1.2341x over previous
//
#include <hip/hip_runtime.h>
#include <hip/hip_bf16.h>

// ---------------------------------------------------------------------------
// SAGE-GCN x3 on MI355X.  Round 8.
//   Agg: XCC-resident quarter planes (r6: FETCH 205->17 MB) restructured for
//     VALU density (r7 was VALU-overhead bound: 38% busy, ~10 instr/edge):
//     - uint4/lane gathers: 4 lanes cover a 64B quarter-row, wave = 16 nodes
//       -> 1 gather instr = 16 edge-visits (1KB), ~1.3 instr/edge-visit.
//     - degree-sorted node permutation (counting sort) -> uniform degree per
//       wave -> unpredicated main loop + short tail.
//     - no cross-lane reduce: each lane owns 8 features of its node.
//   CSR build: bucketed 2-pass (r4).  GEMM: MFMA 16x16x32 bf16, plane-major.
// ---------------------------------------------------------------------------

#define NFEAT 128
#define BKT_CAP 12288
#define CHUNK 64

using bf16x8 = __attribute__((ext_vector_type(8))) short;
using f32x4  = __attribute__((ext_vector_type(4))) float;

__device__ __forceinline__ ushort f2bf(float f) {
    unsigned u = __float_as_uint(f);
    u = (u + 0x7fffu + ((u >> 16) & 1u)) >> 16;
    return (ushort)u;
}
__device__ __forceinline__ float bflo(unsigned v) { return __uint_as_float(v << 16); }
__device__ __forceinline__ float bfhi(unsigned v) { return __uint_as_float(v & 0xffff0000u); }

__device__ __forceinline__ int xcc_id() {
    int x;
    asm volatile("s_getreg_b32 %0, hwreg(HW_REG_XCC_ID)" : "=s"(x));
    return x & 7;
}

// ---------------- CSR build ----------------

__global__ __launch_bounds__(1024) void k_zero_words(int* __restrict__ p, int n) {
    int i = threadIdx.x;
    if (i < n) p[i] = 0;
}

__global__ __launch_bounds__(256) void k_bin(const int* __restrict__ src, const int* __restrict__ dst,
                                             int* __restrict__ gcur, unsigned* __restrict__ pairs, int ne) {
    __shared__ int lcnt[128];
    __shared__ int lbase[128];
    int tid = threadIdx.x;
    if (tid < 128) lcnt[tid] = 0;
    __syncthreads();
    int e0 = blockIdx.x * 4096;
    int myrank[16];
    int mybkt[16];
    unsigned mypair[16];
    #pragma unroll
    for (int i = 0; i < 16; ++i) {
        int e = e0 + tid + i * 256;
        if (e < ne) {
            int s = src[e], d = dst[e];
            int b = d >> 9;
            mybkt[i]  = b;
            mypair[i] = (unsigned)(s & 0xffff) | ((unsigned)(d & 511) << 16);
            myrank[i] = atomicAdd(&lcnt[b], 1);
        } else mybkt[i] = -1;
    }
    __syncthreads();
    if (tid < 128) lbase[tid] = lcnt[tid] ? atomicAdd(&gcur[tid], lcnt[tid]) : 0;
    __syncthreads();
    #pragma unroll
    for (int i = 0; i < 16; ++i) {
        if (mybkt[i] >= 0) {
            int pos = lbase[mybkt[i]] + myrank[i];
            if (pos < BKT_CAP) pairs[(size_t)mybkt[i] * BKT_CAP + pos] = mypair[i];
        }
    }
}

__global__ __launch_bounds__(256) void k_cnt(const unsigned* __restrict__ pairs, const int* __restrict__ gcur,
                                             int* __restrict__ cnt, int n) {
    __shared__ int lcnt[512];
    int b = blockIdx.x, tid = threadIdx.x;
    for (int i = tid; i < 512; i += 256) lcnt[i] = 0;
    __syncthreads();
    int m = gcur[b];
    if (m > BKT_CAP) m = BKT_CAP;
    const unsigned* p = pairs + (size_t)b * BKT_CAP;
    for (int i = tid; i < m; i += 256) atomicAdd(&lcnt[p[i] >> 16], 1);
    __syncthreads();
    int base = b * 512;
    for (int i = tid; i < 512; i += 256) {
        int node = base + i;
        if (node < n) cnt[node] = lcnt[i];
    }
}

__global__ __launch_bounds__(1024) void k_scan_part(const int* __restrict__ cnt, int* __restrict__ part,
                                                    int* __restrict__ tots, int n) {
    __shared__ int wtot[16];
    __shared__ int wpre[16];
    int tid  = threadIdx.x;
    int lane = tid & 63;
    int wv   = tid >> 6;
    int i    = blockIdx.x * 1024 + tid;
    int v    = (i < n) ? cnt[i] : 0;
    int val  = v;
    #pragma unroll
    for (int off = 1; off < 64; off <<= 1) {
        int t = __shfl_up(val, off);
        if (lane >= off) val += t;
    }
    if (lane == 63) wtot[wv] = val;
    __syncthreads();
    if (tid == 0) {
        int s = 0;
        #pragma unroll
        for (int w = 0; w < 16; ++w) { wpre[w] = s; s += wtot[w]; }
        tots[blockIdx.x] = s;
    }
    __syncthreads();
    int excl = val - v + wpre[wv];
    if (i < n) part[i] = excl;
}

__global__ __launch_bounds__(1024) void k_scan_tops(int* __restrict__ tots, int* __restrict__ total_out, int nch) {
    __shared__ int wtot[16];
    __shared__ int wpre[16];
    int tid  = threadIdx.x;
    int lane = tid & 63;
    int wv   = tid >> 6;
    int v    = (tid < nch) ? tots[tid] : 0;
    int val  = v;
    #pragma unroll
    for (int off = 1; off < 64; off <<= 1) {
        int t = __shfl_up(val, off);
        if (lane >= off) val += t;
    }
    if (lane == 63) wtot[wv] = val;
    __syncthreads();
    if (tid == 0) {
        int s = 0;
        #pragma unroll
        for (int w = 0; w < 16; ++w) { wpre[w] = s; s += wtot[w]; }
        *total_out = s;
    }
    __syncthreads();
    int excl = val - v + wpre[wv];
    if (tid < nch) tots[tid] = excl;
}

__global__ __launch_bounds__(1024) void k_scan_add(int* __restrict__ offs, const int* __restrict__ tots, int n) {
    int i = blockIdx.x * 1024 + threadIdx.x;
    if (i < n) offs[i] += tots[blockIdx.x];
}

__global__ __launch_bounds__(256) void k_scatter(const unsigned* __restrict__ pairs, const int* __restrict__ gcur,
                                                 const int* __restrict__ offs, ushort* __restrict__ esrc, int n) {
    __shared__ int lcur[512];
    __shared__ int loffs[512];
    int b = blockIdx.x, tid = threadIdx.x;
    int base = b * 512;
    for (int i = tid; i < 512; i += 256) {
        lcur[i] = 0;
        int node = base + i;
        loffs[i] = (node < n) ? offs[node] : 0;
    }
    __syncthreads();
    int m = gcur[b];
    if (m > BKT_CAP) m = BKT_CAP;
    const unsigned* p = pairs + (size_t)b * BKT_CAP;
    for (int i = tid; i < m; i += 256) {
        unsigned pr = p[i];
        int dlow = pr >> 16;
        int r = atomicAdd(&lcur[dlow], 1);
        esrc[loffs[dlow] + r] = (ushort)(pr & 0xffffu);
    }
}

// ---------------- degree counting-sort -> perm ----------------

__global__ __launch_bounds__(256) void k_dhist(const int* __restrict__ cnt, int* __restrict__ dbin, int n) {
    __shared__ int h[256];
    int tid = threadIdx.x;
    h[tid] = 0;
    __syncthreads();
    int i = blockIdx.x * 256 + tid;
    if (i < n) {
        int b = cnt[i];
        if (b > 255) b = 255;
        atomicAdd(&h[b], 1);
    }
    __syncthreads();
    if (h[tid]) atomicAdd(&dbin[tid], h[tid]);
}

__global__ __launch_bounds__(256) void k_dscan(const int* __restrict__ dbin, int* __restrict__ dcur) {
    __shared__ int wtot[4], wpre[4];
    int tid = threadIdx.x, lane = tid & 63, wv = tid >> 6;
    int v = dbin[tid];
    int val = v;
    #pragma unroll
    for (int off = 1; off < 64; off <<= 1) {
        int t = __shfl_up(val, off);
        if (lane >= off) val += t;
    }
    if (lane == 63) wtot[wv] = val;
    __syncthreads();
    if (tid == 0) {
        int s = 0;
        #pragma unroll
        for (int w = 0; w < 4; ++w) { wpre[w] = s; s += wtot[w]; }
    }
    __syncthreads();
    dcur[tid] = val - v + wpre[wv];
}

__global__ __launch_bounds__(256) void k_dperm(const int* __restrict__ cnt, int* __restrict__ dcur,
                                               int* __restrict__ perm, int n) {
    __shared__ int lh[256];
    __shared__ int lbase[256];
    int tid = threadIdx.x;
    lh[tid] = 0;
    __syncthreads();
    int i = blockIdx.x * 256 + tid;
    int b = 0, myrank = 0;
    if (i < n) {
        b = cnt[i];
        if (b > 255) b = 255;
        myrank = atomicAdd(&lh[b], 1);
    }
    __syncthreads();
    lbase[tid] = lh[tid] ? atomicAdd(&dcur[tid], lh[tid]) : 0;
    __syncthreads();
    if (i < n) perm[lbase[b] + myrank] = i;
}

// ---------------- cast W0|W1|W2 -> bf16 ----------------

__global__ __launch_bounds__(256) void k_cast3(const float* __restrict__ a, int na,
                                               const float* __restrict__ b, int nb,
                                               const float* __restrict__ c, int nc,
                                               ushort* __restrict__ out) {
    int i = blockIdx.x * 256 + threadIdx.x;
    if (i >= na + nb + nc) return;
    float v = (i < na) ? a[i] : ((i < na + nb) ? b[i - na] : c[i - na - nb]);
    out[i] = f2bf(v);
}

// ---------------- GEMM: planes_out[N/32][M][32] = X @ Wb^T ----------------

template <typename InT, int N, bool PLANES_IN>
__global__ __launch_bounds__(256) void k_gemm_mfma(const InT* __restrict__ X, const ushort* __restrict__ Wb,
                                                   ushort* __restrict__ Y, int M) {
    int w    = threadIdx.x >> 6;
    int lane = threadIdx.x & 63;
    int rowf = blockIdx.x * 64 + w * 16 + (lane & 15);
    int kb   = (lane >> 4) * 8;

    bf16x8 a[4];
    if (rowf < M) {
        #pragma unroll
        for (int ks = 0; ks < 4; ++ks) {
            if constexpr (PLANES_IN) {
                a[ks] = *(const bf16x8*)((const ushort*)X + (size_t)ks * M * 32 + (size_t)rowf * 32 + kb);
            } else {
                const float* xp = (const float*)X + (size_t)rowf * 128 + ks * 32 + kb;
                float4 f0 = *(const float4*)xp;
                float4 f1 = *(const float4*)(xp + 4);
                bf16x8 t;
                t[0] = f2bf(f0.x); t[1] = f2bf(f0.y); t[2] = f2bf(f0.z); t[3] = f2bf(f0.w);
                t[4] = f2bf(f1.x); t[5] = f2bf(f1.y); t[6] = f2bf(f1.z); t[7] = f2bf(f1.w);
                a[ks] = t;
            }
        }
    } else {
        #pragma unroll
        for (int ks = 0; ks < 4; ++ks) {
            bf16x8 z = {0, 0, 0, 0, 0, 0, 0, 0};
            a[ks] = z;
        }
    }

    constexpr int NT = N / 16;
    f32x4 acc[NT];
    #pragma unroll
    for (int nt = 0; nt < NT; ++nt) acc[nt] = (f32x4){0.f, 0.f, 0.f, 0.f};

    #pragma unroll
    for (int nt = 0; nt < NT; ++nt) {
        const ushort* wp = Wb + (size_t)(nt * 16 + (lane & 15)) * 128 + kb;
        #pragma unroll
        for (int ks = 0; ks < 4; ++ks) {
            bf16x8 b = *(const bf16x8*)(wp + ks * 32);
            acc[nt] = __builtin_amdgcn_mfma_f32_16x16x32_bf16(a[ks], b, acc[nt], 0, 0, 0);
        }
    }

    int c  = lane & 15;
    int r0 = blockIdx.x * 64 + w * 16 + (lane >> 4) * 4;
    #pragma unroll
    for (int j = 0; j < 4; ++j) {
        int r = r0 + j;
        if (r < M) {
            #pragma unroll
            for (int nt = 0; nt < NT; ++nt)
                Y[(size_t)(nt >> 1) * M * 32 + (size_t)r * 32 + (nt & 1) * 16 + c] = (ushort)f2bf(acc[nt][j]);
        }
    }
}

// ---------------- Aggregation ----------------
// Wave = 16 nodes x 4 lanes; lane sub covers uint4 (8 features) of the 64B
// plane-row.  Degree-sorted perm -> uniform degree per wave.

#define ACC8(T)  { a0 += bflo((T).x); a1 += bfhi((T).x); a2 += bflo((T).y); a3 += bfhi((T).y); \
                   a4 += bflo((T).z); a5 += bfhi((T).z); a6 += bflo((T).w); a7 += bfhi((T).w); }

template <bool RELU>
__global__ __launch_bounds__(256) void k_agg128(const ushort* __restrict__ Yp, const int* __restrict__ offs,
                                                const ushort* __restrict__ esrc, const float* __restrict__ bias,
                                                ushort* __restrict__ Zp, const int* __restrict__ perm,
                                                int* __restrict__ qh, int n, int nchunk) {
    __shared__ int sQ, sT;
    if (threadIdx.x == 0) {
        int pref = xcc_id() & 3;
        int t = -1, qsel = 0;
        #pragma unroll
        for (int a = 0; a < 4; ++a) {
            int cand = (pref + a) & 3;
            int tt = atomicAdd(&qh[cand * 16], 1);
            if (tt < nchunk) { qsel = cand; t = tt; break; }
        }
        sQ = qsel; sT = t;
    }
    __syncthreads();
    int q = sQ, t = sT;
    if (t < 0) return;
    int lane = threadIdx.x & 63;
    int wv   = threadIdx.x >> 6;
    int g    = lane >> 2;
    int sub  = lane & 3;
    int idx  = t * CHUNK + wv * 16 + g;
    bool active = idx < n;
    int nd = 0, start = 0, rem = 0;
    if (active) {
        nd    = perm[idx];
        start = offs[nd];
        rem   = offs[nd + 1] - start;
    }
    const uint4* Y4 = (const uint4*)(Yp + (size_t)q * n * 32);
    uint4*       Z4 = (uint4*)(Zp + (size_t)q * n * 32);

    float a0 = 0.f, a1 = 0.f, a2 = 0.f, a3 = 0.f, a4 = 0.f, a5 = 0.f, a6 = 0.f, a7 = 0.f;

    int minrem = rem, maxrem = rem;
    #pragma unroll
    for (int m = 4; m < 64; m <<= 1) {
        minrem = min(minrem, __shfl_xor(minrem, m));
        maxrem = max(maxrem, __shfl_xor(maxrem, m));
    }

    int r = 0;
    for (; r + 4 <= minrem; r += 4) {       // unpredicated main (sorted -> most work)
        int e = start + r;
        int s0 = esrc[e], s1 = esrc[e + 1], s2 = esrc[e + 2], s3 = esrc[e + 3];
        uint4 t0 = Y4[(size_t)s0 * 4 + sub];
        uint4 t1 = Y4[(size_t)s1 * 4 + sub];
        uint4 t2 = Y4[(size_t)s2 * 4 + sub];
        uint4 t3 = Y4[(size_t)s3 * 4 + sub];
        ACC8(t0); ACC8(t1); ACC8(t2); ACC8(t3);
    }
    for (; r < maxrem; r += 4) {            // predicated tail
        #pragma unroll
        for (int c = 0; c < 4; ++c) {
            int rr = r + c;
            bool val = rr < rem;
            int e = val ? (start + rr) : 0;
            int s = esrc[e];
            uint4 tv = Y4[(size_t)s * 4 + sub];
            if (!val) { tv.x = 0u; tv.y = 0u; tv.z = 0u; tv.w = 0u; }
            ACC8(tv);
        }
    }

    if (active) {
        float scale = 1.0f / (float)(rem + 2);
        uint4 sf = Y4[(size_t)nd * 4 + sub];
        int f0 = q * 32 + sub * 8;
        float4 bA = *(const float4*)&bias[f0];
        float4 bB = *(const float4*)&bias[f0 + 4];
        float r0 = (a0 + 2.f * bflo(sf.x)) * scale + bA.x;
        float r1 = (a1 + 2.f * bfhi(sf.x)) * scale + bA.y;
        float r2 = (a2 + 2.f * bflo(sf.y)) * scale + bA.z;
        float r3 = (a3 + 2.f * bfhi(sf.y)) * scale + bA.w;
        float r4 = (a4 + 2.f * bflo(sf.z)) * scale + bB.x;
        float r5 = (a5 + 2.f * bfhi(sf.z)) * scale + bB.y;
        float r6 = (a6 + 2.f * bflo(sf.w)) * scale + bB.z;
        float r7 = (a7 + 2.f * bfhi(sf.w)) * scale + bB.w;
        if (RELU) {
            r0 = fmaxf(r0, 0.f); r1 = fmaxf(r1, 0.f); r2 = fmaxf(r2, 0.f); r3 = fmaxf(r3, 0.f);
            r4 = fmaxf(r4, 0.f); r5 = fmaxf(r5, 0.f); r6 = fmaxf(r6, 0.f); r7 = fmaxf(r7, 0.f);
        }
        uint4 o;
        o.x = (unsigned)f2bf(r0) | ((unsigned)f2bf(r1) << 16);
        o.y = (unsigned)f2bf(r2) | ((unsigned)f2bf(r3) << 16);
        o.z = (unsigned)f2bf(r4) | ((unsigned)f2bf(r5) << 16);
        o.w = (unsigned)f2bf(r6) | ((unsigned)f2bf(r7) << 16);
        Z4[(size_t)nd * 4 + sub] = o;
    }
}

// Layer-2: 2 half planes, fp32 canonical [n][64] output.
__global__ __launch_bounds__(256) void k_agg64(const ushort* __restrict__ Yp, const int* __restrict__ offs,
                                               const ushort* __restrict__ esrc, const float* __restrict__ bias,
                                               float* __restrict__ Z, const int* __restrict__ perm,
                                               int* __restrict__ qh, int n, int nchunk) {
    __shared__ int sQ, sT;
    if (threadIdx.x == 0) {
        int pref = xcc_id() & 1;
        int t = -1, qsel = 0;
        #pragma unroll
        for (int a = 0; a < 2; ++a) {
            int cand = (pref + a) & 1;
            int tt = atomicAdd(&qh[cand * 16], 1);
            if (tt < nchunk) { qsel = cand; t = tt; break; }
        }
        sQ = qsel; sT = t;
    }
    __syncthreads();
    int h = sQ, t = sT;
    if (t < 0) return;
    int lane = threadIdx.x & 63;
    int wv   = threadIdx.x >> 6;
    int g    = lane >> 2;
    int sub  = lane & 3;
    int idx  = t * CHUNK + wv * 16 + g;
    bool active = idx < n;
    int nd = 0, start = 0, rem = 0;
    if (active) {
        nd    = perm[idx];
        start = offs[nd];
        rem   = offs[nd + 1] - start;
    }
    const uint4* Y4 = (const uint4*)(Yp + (size_t)h * n * 32);

    float a0 = 0.f, a1 = 0.f, a2 = 0.f, a3 = 0.f, a4 = 0.f, a5 = 0.f, a6 = 0.f, a7 = 0.f;

    int minrem = rem, maxrem = rem;
    #pragma unroll
    for (int m = 4; m < 64; m <<= 1) {
        minrem = min(minrem, __shfl_xor(minrem, m));
        maxrem = max(maxrem, __shfl_xor(maxrem, m));
    }

    int r = 0;
    for (; r + 4 <= minrem; r += 4) {
        int e = start + r;
        int s0 = esrc[e], s1 = esrc[e + 1], s2 = esrc[e + 2], s3 = esrc[e + 3];
        uint4 t0 = Y4[(size_t)s0 * 4 + sub];
        uint4 t1 = Y4[(size_t)s1 * 4 + sub];
        uint4 t2 = Y4[(size_t)s2 * 4 + sub];
        uint4 t3 = Y4[(size_t)s3 * 4 + sub];
        ACC8(t0); ACC8(t1); ACC8(t2); ACC8(t3);
    }
    for (; r < maxrem; r += 4) {
        #pragma unroll
        for (int c = 0; c < 4; ++c) {
            int rr = r + c;
            bool val = rr < rem;
            int e = val ? (start + rr) : 0;
            int s = esrc[e];
            uint4 tv = Y4[(size_t)s * 4 + sub];
            if (!val) { tv.x = 0u; tv.y = 0u; tv.z = 0u; tv.w = 0u; }
            ACC8(tv);
        }
    }

    if (active) {
        float scale = 1.0f / (float)(rem + 2);
        uint4 sf = Y4[(size_t)nd * 4 + sub];
        int f0 = h * 32 + sub * 8;
        float4 bA = *(const float4*)&bias[f0];
        float4 bB = *(const float4*)&bias[f0 + 4];
        float4 oA, oB;
        oA.x = (a0 + 2.f * bflo(sf.x)) * scale + bA.x;
        oA.y = (a1 + 2.f * bfhi(sf.x)) * scale + bA.y;
        oA.z = (a2 + 2.f * bflo(sf.y)) * scale + bA.z;
        oA.w = (a3 + 2.f * bfhi(sf.y)) * scale + bA.w;
        oB.x = (a4 + 2.f * bflo(sf.z)) * scale + bB.x;
        oB.y = (a5 + 2.f * bfhi(sf.z)) * scale + bB.y;
        oB.z = (a6 + 2.f * bflo(sf.w)) * scale + bB.z;
        oB.w = (a7 + 2.f * bfhi(sf.w)) * scale + bB.w;
        float* zr = Z + (size_t)nd * 64 + f0;
        *(float4*)zr       = oA;
        *(float4*)(zr + 4) = oB;
    }
}

// ---------------- launch ----------------

extern "C" void kernel_launch(void* const* d_in, const int* in_sizes, int n_in,
                              void* d_out, int out_size, void* d_ws, size_t ws_size,
                              hipStream_t stream) {
    const float* in_feat = (const float*)d_in[0];
    const int*   src     = (const int*)d_in[1];
    const int*   dst     = (const int*)d_in[2];
    const float* W0      = (const float*)d_in[3];
    const float* b0      = (const float*)d_in[4];
    const float* W1      = (const float*)d_in[5];
    const float* b1      = (const float*)d_in[6];
    const float* W2      = (const float*)d_in[7];
    const float* b2      = (const float*)d_in[8];
    float* out = (float*)d_out;

    const int n  = in_sizes[0] / NFEAT;   // 50000 (<= 65536 assumed)
    const int ne = in_sizes[1];           // 800000
    const int nch = (n + 1023) / 1024;
    const int NB  = (n + 511) >> 9;
    const int nblk256 = (n + 255) / 256;
    const int nchunk = (n + CHUNK - 1) / CHUNK;

    // workspace carve (16B aligned)
    int* offs       = (int*)d_ws;                          // n+1
    int* tots       = offs + (((n + 1) + 3) & ~3);         // 1024
    int* gcur       = tots + 1024;                         // 128
    int* qh         = gcur + 128;                          // 192 claim counters
    int* dbin       = qh + 192;                            // 256
    int* dcur       = dbin + 256;                          // 256
    int* cnt        = dcur + 256;                          // n
    int* perm       = cnt + ((n + 3) & ~3);                // n
    unsigned* pairs = (unsigned*)(perm + ((n + 3) & ~3));  // 128*BKT_CAP
    ushort* esrc    = (ushort*)(pairs + (size_t)128 * BKT_CAP);  // ne (+pad)
    ushort* Wb      = esrc + ((ne + 15) & ~15);            // 40960
    ushort* Ybuf    = Wb + 40960;                          // n*128 plane-major
    ushort* Zbuf    = Ybuf + (size_t)n * NFEAT;            // n*128 plane-major

    // --- CSR build + degree sort ---
    k_zero_words<<<1, 1024, 0, stream>>>(gcur, 128 + 192 + 256);
    k_bin<<<(ne + 4095) / 4096, 256, 0, stream>>>(src, dst, gcur, pairs, ne);
    k_cnt<<<NB, 256, 0, stream>>>(pairs, gcur, cnt, n);
    k_dhist<<<nblk256, 256, 0, stream>>>(cnt, dbin, n);
    k_dscan<<<1, 256, 0, stream>>>(dbin, dcur);
    k_dperm<<<nblk256, 256, 0, stream>>>(cnt, dcur, perm, n);
    k_scan_part<<<nch, 1024, 0, stream>>>(cnt, offs, tots, n);
    k_scan_tops<<<1, 1024, 0, stream>>>(tots, offs + n, nch);
    k_scan_add<<<nch, 1024, 0, stream>>>(offs, tots, n);
    k_scatter<<<NB, 256, 0, stream>>>(pairs, gcur, offs, esrc, n);

    // --- weights -> bf16 ---
    k_cast3<<<(40960 + 255) / 256, 256, 0, stream>>>(W0, 16384, W1, 16384, W2, 8192, Wb);
    const ushort* Wb0 = Wb;
    const ushort* Wb1 = Wb + 16384;
    const ushort* Wb2 = Wb + 32768;

    const int gg = (n + 63) / 64;

    // --- layer 0 ---
    k_gemm_mfma<float, 128, false><<<gg, 256, 0, stream>>>(in_feat, Wb0, Ybuf, n);
    k_agg128<true><<<4 * nchunk, 256, 0, stream>>>(Ybuf, offs, esrc, b0, Zbuf, perm, qh, n, nchunk);
    // --- layer 1 ---
    k_gemm_mfma<ushort, 128, true><<<gg, 256, 0, stream>>>(Zbuf, Wb1, Ybuf, n);
    k_agg128<true><<<4 * nchunk, 256, 0, stream>>>(Ybuf, offs, esrc, b1, Zbuf, perm, qh + 64, n, nchunk);
    // --- layer 2 (N=64, no relu, fp32 out) ---
    k_gemm_mfma<ushort, 64, true><<<gg, 256, 0, stream>>>(Zbuf, Wb2, Ybuf, n);
    k_agg64<<<2 * nchunk, 256, 0, stream>>>(Ybuf, offs, esrc, b2, out, perm, qh + 128, n, nchunk);

    (void)ws_size; (void)n_in; (void)out_size;
}

// Round 9
// 222.099 us; speedup vs baseline: 1.4798x; 1.1253x over previous
//
#include <hip/hip_runtime.h>
#include <hip/hip_bf16.h>

// ---------------------------------------------------------------------------
// SAGE-GCN x3 on MI355X.  Round 9.
//   Agg: XCC-resident quarter planes + uint4/lane gathers (r8: VALU 38->16%)
//     with WINDOWED degree sort (r8's global sort scattered offs/esrc/self
//     accesses -> FETCH 19->52 MB; sorting within 1024-node windows keeps
//     locality AND wave-degree uniformity) and 8-deep edge unroll.
//   CSR build: bucketed 2-pass (r4).  GEMM: MFMA 16x16x32 bf16, plane-major.
// ---------------------------------------------------------------------------

#define NFEAT 128
#define BKT_CAP 12288
#define CHUNK 64

using bf16x8 = __attribute__((ext_vector_type(8))) short;
using f32x4  = __attribute__((ext_vector_type(4))) float;

__device__ __forceinline__ ushort f2bf(float f) {
    unsigned u = __float_as_uint(f);
    u = (u + 0x7fffu + ((u >> 16) & 1u)) >> 16;
    return (ushort)u;
}
__device__ __forceinline__ float bflo(unsigned v) { return __uint_as_float(v << 16); }
__device__ __forceinline__ float bfhi(unsigned v) { return __uint_as_float(v & 0xffff0000u); }

__device__ __forceinline__ int xcc_id() {
    int x;
    asm volatile("s_getreg_b32 %0, hwreg(HW_REG_XCC_ID)" : "=s"(x));
    return x & 7;
}

// ---------------- CSR build ----------------

__global__ __launch_bounds__(1024) void k_zero_words(int* __restrict__ p, int n) {
    int i = threadIdx.x;
    if (i < n) p[i] = 0;
}

__global__ __launch_bounds__(256) void k_bin(const int* __restrict__ src, const int* __restrict__ dst,
                                             int* __restrict__ gcur, unsigned* __restrict__ pairs, int ne) {
    __shared__ int lcnt[128];
    __shared__ int lbase[128];
    int tid = threadIdx.x;
    if (tid < 128) lcnt[tid] = 0;
    __syncthreads();
    int e0 = blockIdx.x * 4096;
    int myrank[16];
    int mybkt[16];
    unsigned mypair[16];
    #pragma unroll
    for (int i = 0; i < 16; ++i) {
        int e = e0 + tid + i * 256;
        if (e < ne) {
            int s = src[e], d = dst[e];
            int b = d >> 9;
            mybkt[i]  = b;
            mypair[i] = (unsigned)(s & 0xffff) | ((unsigned)(d & 511) << 16);
            myrank[i] = atomicAdd(&lcnt[b], 1);
        } else mybkt[i] = -1;
    }
    __syncthreads();
    if (tid < 128) lbase[tid] = lcnt[tid] ? atomicAdd(&gcur[tid], lcnt[tid]) : 0;
    __syncthreads();
    #pragma unroll
    for (int i = 0; i < 16; ++i) {
        if (mybkt[i] >= 0) {
            int pos = lbase[mybkt[i]] + myrank[i];
            if (pos < BKT_CAP) pairs[(size_t)mybkt[i] * BKT_CAP + pos] = mypair[i];
        }
    }
}

__global__ __launch_bounds__(256) void k_cnt(const unsigned* __restrict__ pairs, const int* __restrict__ gcur,
                                             int* __restrict__ cnt, int n) {
    __shared__ int lcnt[512];
    int b = blockIdx.x, tid = threadIdx.x;
    for (int i = tid; i < 512; i += 256) lcnt[i] = 0;
    __syncthreads();
    int m = gcur[b];
    if (m > BKT_CAP) m = BKT_CAP;
    const unsigned* p = pairs + (size_t)b * BKT_CAP;
    for (int i = tid; i < m; i += 256) atomicAdd(&lcnt[p[i] >> 16], 1);
    __syncthreads();
    int base = b * 512;
    for (int i = tid; i < 512; i += 256) {
        int node = base + i;
        if (node < n) cnt[node] = lcnt[i];
    }
}

__global__ __launch_bounds__(1024) void k_scan_part(const int* __restrict__ cnt, int* __restrict__ part,
                                                    int* __restrict__ tots, int n) {
    __shared__ int wtot[16];
    __shared__ int wpre[16];
    int tid  = threadIdx.x;
    int lane = tid & 63;
    int wv   = tid >> 6;
    int i    = blockIdx.x * 1024 + tid;
    int v    = (i < n) ? cnt[i] : 0;
    int val  = v;
    #pragma unroll
    for (int off = 1; off < 64; off <<= 1) {
        int t = __shfl_up(val, off);
        if (lane >= off) val += t;
    }
    if (lane == 63) wtot[wv] = val;
    __syncthreads();
    if (tid == 0) {
        int s = 0;
        #pragma unroll
        for (int w = 0; w < 16; ++w) { wpre[w] = s; s += wtot[w]; }
        tots[blockIdx.x] = s;
    }
    __syncthreads();
    int excl = val - v + wpre[wv];
    if (i < n) part[i] = excl;
}

__global__ __launch_bounds__(1024) void k_scan_tops(int* __restrict__ tots, int* __restrict__ total_out, int nch) {
    __shared__ int wtot[16];
    __shared__ int wpre[16];
    int tid  = threadIdx.x;
    int lane = tid & 63;
    int wv   = tid >> 6;
    int v    = (tid < nch) ? tots[tid] : 0;
    int val  = v;
    #pragma unroll
    for (int off = 1; off < 64; off <<= 1) {
        int t = __shfl_up(val, off);
        if (lane >= off) val += t;
    }
    if (lane == 63) wtot[wv] = val;
    __syncthreads();
    if (tid == 0) {
        int s = 0;
        #pragma unroll
        for (int w = 0; w < 16; ++w) { wpre[w] = s; s += wtot[w]; }
        *total_out = s;
    }
    __syncthreads();
    int excl = val - v + wpre[wv];
    if (tid < nch) tots[tid] = excl;
}

__global__ __launch_bounds__(1024) void k_scan_add(int* __restrict__ offs, const int* __restrict__ tots, int n) {
    int i = blockIdx.x * 1024 + threadIdx.x;
    if (i < n) offs[i] += tots[blockIdx.x];
}

__global__ __launch_bounds__(256) void k_scatter(const unsigned* __restrict__ pairs, const int* __restrict__ gcur,
                                                 const int* __restrict__ offs, ushort* __restrict__ esrc, int n) {
    __shared__ int lcur[512];
    __shared__ int loffs[512];
    int b = blockIdx.x, tid = threadIdx.x;
    int base = b * 512;
    for (int i = tid; i < 512; i += 256) {
        lcur[i] = 0;
        int node = base + i;
        loffs[i] = (node < n) ? offs[node] : 0;
    }
    __syncthreads();
    int m = gcur[b];
    if (m > BKT_CAP) m = BKT_CAP;
    const unsigned* p = pairs + (size_t)b * BKT_CAP;
    for (int i = tid; i < m; i += 256) {
        unsigned pr = p[i];
        int dlow = pr >> 16;
        int r = atomicAdd(&lcur[dlow], 1);
        esrc[loffs[dlow] + r] = (ushort)(pr & 0xffffu);
    }
}

// ---------------- windowed degree sort -> perm ----------------
// Per 1024-node window: counting-sort node ids by (clamped) degree.
// Keeps wave-degree uniformity while preserving ~window locality.

__global__ __launch_bounds__(1024) void k_dsort_win(const int* __restrict__ cnt, int* __restrict__ perm, int n) {
    __shared__ int hist[256];
    __shared__ int hcur[256];
    __shared__ int wtot[16];
    __shared__ int wpre[16];
    int tid  = threadIdx.x;
    int base = blockIdx.x * 1024;
    if (tid < 256) hist[tid] = 0;
    __syncthreads();
    int i = base + tid;
    bool act = i < n;
    int d = 0, rank = 0;
    if (act) {
        d = cnt[i];
        if (d > 255) d = 255;
        rank = atomicAdd(&hist[d], 1);
    }
    __syncthreads();
    // exclusive scan of hist[256] (all 1024 threads participate; waves 4..15 carry zeros)
    int lane = tid & 63;
    int wv   = tid >> 6;
    int v    = (tid < 256) ? hist[tid] : 0;
    int val  = v;
    #pragma unroll
    for (int off = 1; off < 64; off <<= 1) {
        int t = __shfl_up(val, off);
        if (lane >= off) val += t;
    }
    if (lane == 63) wtot[wv] = val;
    __syncthreads();
    if (tid == 0) {
        int s = 0;
        #pragma unroll
        for (int w = 0; w < 4; ++w) { wpre[w] = s; s += wtot[w]; }
    }
    __syncthreads();
    if (tid < 256) hcur[tid] = val - v + wpre[wv];
    __syncthreads();
    if (act) perm[base + hcur[d] + rank] = i;
}

// ---------------- cast W0|W1|W2 -> bf16 ----------------

__global__ __launch_bounds__(256) void k_cast3(const float* __restrict__ a, int na,
                                               const float* __restrict__ b, int nb,
                                               const float* __restrict__ c, int nc,
                                               ushort* __restrict__ out) {
    int i = blockIdx.x * 256 + threadIdx.x;
    if (i >= na + nb + nc) return;
    float v = (i < na) ? a[i] : ((i < na + nb) ? b[i - na] : c[i - na - nb]);
    out[i] = f2bf(v);
}

// ---------------- GEMM: planes_out[N/32][M][32] = X @ Wb^T ----------------

template <typename InT, int N, bool PLANES_IN>
__global__ __launch_bounds__(256) void k_gemm_mfma(const InT* __restrict__ X, const ushort* __restrict__ Wb,
                                                   ushort* __restrict__ Y, int M) {
    int w    = threadIdx.x >> 6;
    int lane = threadIdx.x & 63;
    int rowf = blockIdx.x * 64 + w * 16 + (lane & 15);
    int kb   = (lane >> 4) * 8;

    bf16x8 a[4];
    if (rowf < M) {
        #pragma unroll
        for (int ks = 0; ks < 4; ++ks) {
            if constexpr (PLANES_IN) {
                a[ks] = *(const bf16x8*)((const ushort*)X + (size_t)ks * M * 32 + (size_t)rowf * 32 + kb);
            } else {
                const float* xp = (const float*)X + (size_t)rowf * 128 + ks * 32 + kb;
                float4 f0 = *(const float4*)xp;
                float4 f1 = *(const float4*)(xp + 4);
                bf16x8 t;
                t[0] = f2bf(f0.x); t[1] = f2bf(f0.y); t[2] = f2bf(f0.z); t[3] = f2bf(f0.w);
                t[4] = f2bf(f1.x); t[5] = f2bf(f1.y); t[6] = f2bf(f1.z); t[7] = f2bf(f1.w);
                a[ks] = t;
            }
        }
    } else {
        #pragma unroll
        for (int ks = 0; ks < 4; ++ks) {
            bf16x8 z = {0, 0, 0, 0, 0, 0, 0, 0};
            a[ks] = z;
        }
    }

    constexpr int NT = N / 16;
    f32x4 acc[NT];
    #pragma unroll
    for (int nt = 0; nt < NT; ++nt) acc[nt] = (f32x4){0.f, 0.f, 0.f, 0.f};

    #pragma unroll
    for (int nt = 0; nt < NT; ++nt) {
        const ushort* wp = Wb + (size_t)(nt * 16 + (lane & 15)) * 128 + kb;
        #pragma unroll
        for (int ks = 0; ks < 4; ++ks) {
            bf16x8 b = *(const bf16x8*)(wp + ks * 32);
            acc[nt] = __builtin_amdgcn_mfma_f32_16x16x32_bf16(a[ks], b, acc[nt], 0, 0, 0);
        }
    }

    int c  = lane & 15;
    int r0 = blockIdx.x * 64 + w * 16 + (lane >> 4) * 4;
    #pragma unroll
    for (int j = 0; j < 4; ++j) {
        int r = r0 + j;
        if (r < M) {
            #pragma unroll
            for (int nt = 0; nt < NT; ++nt)
                Y[(size_t)(nt >> 1) * M * 32 + (size_t)r * 32 + (nt & 1) * 16 + c] = (ushort)f2bf(acc[nt][j]);
        }
    }
}

// ---------------- Aggregation ----------------
// Wave = 16 nodes x 4 lanes; lane sub covers uint4 (8 feats) of the 64B
// plane-row.  Window-sorted perm -> uniform degree per wave + locality.

#define ACC8(T)  { a0 += bflo((T).x); a1 += bfhi((T).x); a2 += bflo((T).y); a3 += bfhi((T).y); \
                   a4 += bflo((T).z); a5 += bfhi((T).z); a6 += bflo((T).w); a7 += bfhi((T).w); }

template <bool RELU>
__global__ __launch_bounds__(256) void k_agg128(const ushort* __restrict__ Yp, const int* __restrict__ offs,
                                                const ushort* __restrict__ esrc, const float* __restrict__ bias,
                                                ushort* __restrict__ Zp, const int* __restrict__ perm,
                                                int* __restrict__ qh, int n, int nchunk) {
    __shared__ int sQ, sT;
    if (threadIdx.x == 0) {
        int pref = xcc_id() & 3;
        int t = -1, qsel = 0;
        #pragma unroll
        for (int a = 0; a < 4; ++a) {
            int cand = (pref + a) & 3;
            int tt = atomicAdd(&qh[cand * 16], 1);
            if (tt < nchunk) { qsel = cand; t = tt; break; }
        }
        sQ = qsel; sT = t;
    }
    __syncthreads();
    int q = sQ, t = sT;
    if (t < 0) return;
    int lane = threadIdx.x & 63;
    int wv   = threadIdx.x >> 6;
    int g    = lane >> 2;
    int sub  = lane & 3;
    int idx  = t * CHUNK + wv * 16 + g;
    bool active = idx < n;
    int nd = 0, start = 0, rem = 0;
    if (active) {
        nd    = perm[idx];
        start = offs[nd];
        rem   = offs[nd + 1] - start;
    }
    const uint4* Y4 = (const uint4*)(Yp + (size_t)q * n * 32);
    uint4*       Z4 = (uint4*)(Zp + (size_t)q * n * 32);

    float a0 = 0.f, a1 = 0.f, a2 = 0.f, a3 = 0.f, a4 = 0.f, a5 = 0.f, a6 = 0.f, a7 = 0.f;

    int minrem = rem, maxrem = rem;
    #pragma unroll
    for (int m = 4; m < 64; m <<= 1) {
        minrem = min(minrem, __shfl_xor(minrem, m));
        maxrem = max(maxrem, __shfl_xor(maxrem, m));
    }

    int r = 0;
    for (; r + 8 <= minrem; r += 8) {       // 8 gathers in flight/lane
        int e = start + r;
        int s0 = esrc[e],     s1 = esrc[e + 1], s2 = esrc[e + 2], s3 = esrc[e + 3];
        int s4 = esrc[e + 4], s5 = esrc[e + 5], s6 = esrc[e + 6], s7 = esrc[e + 7];
        uint4 t0 = Y4[(size_t)s0 * 4 + sub];
        uint4 t1 = Y4[(size_t)s1 * 4 + sub];
        uint4 t2 = Y4[(size_t)s2 * 4 + sub];
        uint4 t3 = Y4[(size_t)s3 * 4 + sub];
        uint4 t4 = Y4[(size_t)s4 * 4 + sub];
        uint4 t5 = Y4[(size_t)s5 * 4 + sub];
        uint4 t6 = Y4[(size_t)s6 * 4 + sub];
        uint4 t7 = Y4[(size_t)s7 * 4 + sub];
        ACC8(t0); ACC8(t1); ACC8(t2); ACC8(t3); ACC8(t4); ACC8(t5); ACC8(t6); ACC8(t7);
    }
    for (; r + 4 <= minrem; r += 4) {
        int e = start + r;
        int s0 = esrc[e], s1 = esrc[e + 1], s2 = esrc[e + 2], s3 = esrc[e + 3];
        uint4 t0 = Y4[(size_t)s0 * 4 + sub];
        uint4 t1 = Y4[(size_t)s1 * 4 + sub];
        uint4 t2 = Y4[(size_t)s2 * 4 + sub];
        uint4 t3 = Y4[(size_t)s3 * 4 + sub];
        ACC8(t0); ACC8(t1); ACC8(t2); ACC8(t3);
    }
    for (; r < maxrem; r += 4) {            // predicated tail
        #pragma unroll
        for (int c = 0; c < 4; ++c) {
            int rr = r + c;
            bool val = rr < rem;
            int e = val ? (start + rr) : 0;
            int s = esrc[e];
            uint4 tv = Y4[(size_t)s * 4 + sub];
            if (!val) { tv.x = 0u; tv.y = 0u; tv.z = 0u; tv.w = 0u; }
            ACC8(tv);
        }
    }

    if (active) {
        float scale = 1.0f / (float)(rem + 2);
        uint4 sf = Y4[(size_t)nd * 4 + sub];
        int f0 = q * 32 + sub * 8;
        float4 bA = *(const float4*)&bias[f0];
        float4 bB = *(const float4*)&bias[f0 + 4];
        float r0 = (a0 + 2.f * bflo(sf.x)) * scale + bA.x;
        float r1 = (a1 + 2.f * bfhi(sf.x)) * scale + bA.y;
        float r2 = (a2 + 2.f * bflo(sf.y)) * scale + bA.z;
        float r3 = (a3 + 2.f * bfhi(sf.y)) * scale + bA.w;
        float r4 = (a4 + 2.f * bflo(sf.z)) * scale + bB.x;
        float r5 = (a5 + 2.f * bfhi(sf.z)) * scale + bB.y;
        float r6 = (a6 + 2.f * bflo(sf.w)) * scale + bB.z;
        float r7 = (a7 + 2.f * bfhi(sf.w)) * scale + bB.w;
        if (RELU) {
            r0 = fmaxf(r0, 0.f); r1 = fmaxf(r1, 0.f); r2 = fmaxf(r2, 0.f); r3 = fmaxf(r3, 0.f);
            r4 = fmaxf(r4, 0.f); r5 = fmaxf(r5, 0.f); r6 = fmaxf(r6, 0.f); r7 = fmaxf(r7, 0.f);
        }
        uint4 o;
        o.x = (unsigned)f2bf(r0) | ((unsigned)f2bf(r1) << 16);
        o.y = (unsigned)f2bf(r2) | ((unsigned)f2bf(r3) << 16);
        o.z = (unsigned)f2bf(r4) | ((unsigned)f2bf(r5) << 16);
        o.w = (unsigned)f2bf(r6) | ((unsigned)f2bf(r7) << 16);
        Z4[(size_t)nd * 4 + sub] = o;
    }
}

// Layer-2: 2 half planes, fp32 canonical [n][64] output.
__global__ __launch_bounds__(256) void k_agg64(const ushort* __restrict__ Yp, const int* __restrict__ offs,
                                               const ushort* __restrict__ esrc, const float* __restrict__ bias,
                                               float* __restrict__ Z, const int* __restrict__ perm,
                                               int* __restrict__ qh, int n, int nchunk) {
    __shared__ int sQ, sT;
    if (threadIdx.x == 0) {
        int pref = xcc_id() & 1;
        int t = -1, qsel = 0;
        #pragma unroll
        for (int a = 0; a < 2; ++a) {
            int cand = (pref + a) & 1;
            int tt = atomicAdd(&qh[cand * 16], 1);
            if (tt < nchunk) { qsel = cand; t = tt; break; }
        }
        sQ = qsel; sT = t;
    }
    __syncthreads();
    int h = sQ, t = sT;
    if (t < 0) return;
    int lane = threadIdx.x & 63;
    int wv   = threadIdx.x >> 6;
    int g    = lane >> 2;
    int sub  = lane & 3;
    int idx  = t * CHUNK + wv * 16 + g;
    bool active = idx < n;
    int nd = 0, start = 0, rem = 0;
    if (active) {
        nd    = perm[idx];
        start = offs[nd];
        rem   = offs[nd + 1] - start;
    }
    const uint4* Y4 = (const uint4*)(Yp + (size_t)h * n * 32);

    float a0 = 0.f, a1 = 0.f, a2 = 0.f, a3 = 0.f, a4 = 0.f, a5 = 0.f, a6 = 0.f, a7 = 0.f;

    int minrem = rem, maxrem = rem;
    #pragma unroll
    for (int m = 4; m < 64; m <<= 1) {
        minrem = min(minrem, __shfl_xor(minrem, m));
        maxrem = max(maxrem, __shfl_xor(maxrem, m));
    }

    int r = 0;
    for (; r + 8 <= minrem; r += 8) {
        int e = start + r;
        int s0 = esrc[e],     s1 = esrc[e + 1], s2 = esrc[e + 2], s3 = esrc[e + 3];
        int s4 = esrc[e + 4], s5 = esrc[e + 5], s6 = esrc[e + 6], s7 = esrc[e + 7];
        uint4 t0 = Y4[(size_t)s0 * 4 + sub];
        uint4 t1 = Y4[(size_t)s1 * 4 + sub];
        uint4 t2 = Y4[(size_t)s2 * 4 + sub];
        uint4 t3 = Y4[(size_t)s3 * 4 + sub];
        uint4 t4 = Y4[(size_t)s4 * 4 + sub];
        uint4 t5 = Y4[(size_t)s5 * 4 + sub];
        uint4 t6 = Y4[(size_t)s6 * 4 + sub];
        uint4 t7 = Y4[(size_t)s7 * 4 + sub];
        ACC8(t0); ACC8(t1); ACC8(t2); ACC8(t3); ACC8(t4); ACC8(t5); ACC8(t6); ACC8(t7);
    }
    for (; r + 4 <= minrem; r += 4) {
        int e = start + r;
        int s0 = esrc[e], s1 = esrc[e + 1], s2 = esrc[e + 2], s3 = esrc[e + 3];
        uint4 t0 = Y4[(size_t)s0 * 4 + sub];
        uint4 t1 = Y4[(size_t)s1 * 4 + sub];
        uint4 t2 = Y4[(size_t)s2 * 4 + sub];
        uint4 t3 = Y4[(size_t)s3 * 4 + sub];
        ACC8(t0); ACC8(t1); ACC8(t2); ACC8(t3);
    }
    for (; r < maxrem; r += 4) {
        #pragma unroll
        for (int c = 0; c < 4; ++c) {
            int rr = r + c;
            bool val = rr < rem;
            int e = val ? (start + rr) : 0;
            int s = esrc[e];
            uint4 tv = Y4[(size_t)s * 4 + sub];
            if (!val) { tv.x = 0u; tv.y = 0u; tv.z = 0u; tv.w = 0u; }
            ACC8(tv);
        }
    }

    if (active) {
        float scale = 1.0f / (float)(rem + 2);
        uint4 sf = Y4[(size_t)nd * 4 + sub];
        int f0 = h * 32 + sub * 8;
        float4 bA = *(const float4*)&bias[f0];
        float4 bB = *(const float4*)&bias[f0 + 4];
        float4 oA, oB;
        oA.x = (a0 + 2.f * bflo(sf.x)) * scale + bA.x;
        oA.y = (a1 + 2.f * bfhi(sf.x)) * scale + bA.y;
        oA.z = (a2 + 2.f * bflo(sf.y)) * scale + bA.z;
        oA.w = (a3 + 2.f * bfhi(sf.y)) * scale + bA.w;
        oB.x = (a4 + 2.f * bflo(sf.z)) * scale + bB.x;
        oB.y = (a5 + 2.f * bfhi(sf.z)) * scale + bB.y;
        oB.z = (a6 + 2.f * bflo(sf.w)) * scale + bB.z;
        oB.w = (a7 + 2.f * bfhi(sf.w)) * scale + bB.w;
        float* zr = Z + (size_t)nd * 64 + f0;
        *(float4*)zr       = oA;
        *(float4*)(zr + 4) = oB;
    }
}

// ---------------- launch ----------------

extern "C" void kernel_launch(void* const* d_in, const int* in_sizes, int n_in,
                              void* d_out, int out_size, void* d_ws, size_t ws_size,
                              hipStream_t stream) {
    const float* in_feat = (const float*)d_in[0];
    const int*   src     = (const int*)d_in[1];
    const int*   dst     = (const int*)d_in[2];
    const float* W0      = (const float*)d_in[3];
    const float* b0      = (const float*)d_in[4];
    const float* W1      = (const float*)d_in[5];
    const float* b1      = (const float*)d_in[6];
    const float* W2      = (const float*)d_in[7];
    const float* b2      = (const float*)d_in[8];
    float* out = (float*)d_out;

    const int n  = in_sizes[0] / NFEAT;   // 50000 (<= 65536 assumed)
    const int ne = in_sizes[1];           // 800000
    const int nch = (n + 1023) / 1024;
    const int NB  = (n + 511) >> 9;
    const int nchunk = (n + CHUNK - 1) / CHUNK;

    // workspace carve (16B aligned)
    int* offs       = (int*)d_ws;                          // n+1
    int* tots       = offs + (((n + 1) + 3) & ~3);         // 1024
    int* gcur       = tots + 1024;                         // 128
    int* qh         = gcur + 128;                          // 192 claim counters
    int* cnt        = qh + 192;                            // n
    int* perm       = cnt + ((n + 3) & ~3);                // n
    unsigned* pairs = (unsigned*)(perm + ((n + 3) & ~3));  // 128*BKT_CAP
    ushort* esrc    = (ushort*)(pairs + (size_t)128 * BKT_CAP);  // ne (+pad)
    ushort* Wb      = esrc + ((ne + 15) & ~15);            // 40960
    ushort* Ybuf    = Wb + 40960;                          // n*128 plane-major
    ushort* Zbuf    = Ybuf + (size_t)n * NFEAT;            // n*128 plane-major

    // --- CSR build + windowed degree sort ---
    k_zero_words<<<1, 1024, 0, stream>>>(gcur, 128 + 192);
    k_bin<<<(ne + 4095) / 4096, 256, 0, stream>>>(src, dst, gcur, pairs, ne);
    k_cnt<<<NB, 256, 0, stream>>>(pairs, gcur, cnt, n);
    k_dsort_win<<<nch, 1024, 0, stream>>>(cnt, perm, n);
    k_scan_part<<<nch, 1024, 0, stream>>>(cnt, offs, tots, n);
    k_scan_tops<<<1, 1024, 0, stream>>>(tots, offs + n, nch);
    k_scan_add<<<nch, 1024, 0, stream>>>(offs, tots, n);
    k_scatter<<<NB, 256, 0, stream>>>(pairs, gcur, offs, esrc, n);

    // --- weights -> bf16 ---
    k_cast3<<<(40960 + 255) / 256, 256, 0, stream>>>(W0, 16384, W1, 16384, W2, 8192, Wb);
    const ushort* Wb0 = Wb;
    const ushort* Wb1 = Wb + 16384;
    const ushort* Wb2 = Wb + 32768;

    const int gg = (n + 63) / 64;

    // --- layer 0 ---
    k_gemm_mfma<float, 128, false><<<gg, 256, 0, stream>>>(in_feat, Wb0, Ybuf, n);
    k_agg128<true><<<4 * nchunk, 256, 0, stream>>>(Ybuf, offs, esrc, b0, Zbuf, perm, qh, n, nchunk);
    // --- layer 1 ---
    k_gemm_mfma<ushort, 128, true><<<gg, 256, 0, stream>>>(Zbuf, Wb1, Ybuf, n);
    k_agg128<true><<<4 * nchunk, 256, 0, stream>>>(Ybuf, offs, esrc, b1, Zbuf, perm, qh + 64, n, nchunk);
    // --- layer 2 (N=64, no relu, fp32 out) ---
    k_gemm_mfma<ushort, 64, true><<<gg, 256, 0, stream>>>(Zbuf, Wb2, Ybuf, n);
    k_agg64<<<2 * nchunk, 256, 0, stream>>>(Ybuf, offs, esrc, b2, out, perm, qh + 128, n, nchunk);

    (void)ws_size; (void)n_in; (void)out_size;
}

// Round 10
// 221.200 us; speedup vs baseline: 1.4858x; 1.0041x over previous
//
#include <hip/hip_runtime.h>
#include <hip/hip_bf16.h>

// ---------------------------------------------------------------------------
// SAGE-GCN x3 on MI355X.  Round 10.
//   Agg: XCC-resident quarter planes (r6), uint4/lane gathers (r8), windowed
//     degree sort (r9) + NEW: 8-aligned CSR segments with sentinel padding
//     (index n -> zeroed row) => branchless inner loop, uint4 index-block
//     loads (1 per 8 edges), one-ahead prefetch, no tail predication.
//   CSR: bucketed 2-pass; window sort+padded scan fused (k_prep_win);
//     all zero/fill init fused (k_init).
//   GEMM: MFMA 16x16x32 bf16, plane-major with (n+1)-row planes.
// ---------------------------------------------------------------------------

#define NFEAT 128
#define BKT_CAP 12288
#define CHUNK 64

using bf16x8 = __attribute__((ext_vector_type(8))) short;
using f32x4  = __attribute__((ext_vector_type(4))) float;

__device__ __forceinline__ ushort f2bf(float f) {
    unsigned u = __float_as_uint(f);
    u = (u + 0x7fffu + ((u >> 16) & 1u)) >> 16;
    return (ushort)u;
}
__device__ __forceinline__ float bflo(unsigned v) { return __uint_as_float(v << 16); }
__device__ __forceinline__ float bfhi(unsigned v) { return __uint_as_float(v & 0xffff0000u); }

__device__ __forceinline__ int xcc_id() {
    int x;
    asm volatile("s_getreg_b32 %0, hwreg(HW_REG_XCC_ID)" : "=s"(x));
    return x & 7;
}

// ---------------- init: ctl zeros + esrc sentinel fill + plane sentinel rows ----------------

__global__ __launch_bounds__(256) void k_init(unsigned* __restrict__ esrc_u32, int fillN, unsigned sent2,
                                              int* __restrict__ ctl, ushort* __restrict__ Ybuf, int n) {
    int i = blockIdx.x * 256 + threadIdx.x;
    if (i < fillN) {
        esrc_u32[i] = sent2;
    } else if (i < fillN + 320) {
        ctl[i - fillN] = 0;
    } else if (i < fillN + 320 + 64) {
        int j = i - fillN - 320;      // 4 planes x 16 uints (32 ushorts = 64B row)
        int p = j >> 4, k = j & 15;
        ((unsigned*)(Ybuf + (size_t)p * (n + 1) * 32 + (size_t)n * 32))[k] = 0u;
    }
}

// ---------------- CSR build ----------------

__global__ __launch_bounds__(256) void k_bin(const int* __restrict__ src, const int* __restrict__ dst,
                                             int* __restrict__ gcur, unsigned* __restrict__ pairs, int ne) {
    __shared__ int lcnt[128];
    __shared__ int lbase[128];
    int tid = threadIdx.x;
    if (tid < 128) lcnt[tid] = 0;
    __syncthreads();
    int e0 = blockIdx.x * 4096;
    int myrank[16];
    int mybkt[16];
    unsigned mypair[16];
    #pragma unroll
    for (int i = 0; i < 16; ++i) {
        int e = e0 + tid + i * 256;
        if (e < ne) {
            int s = src[e], d = dst[e];
            int b = d >> 9;
            mybkt[i]  = b;
            mypair[i] = (unsigned)(s & 0xffff) | ((unsigned)(d & 511) << 16);
            myrank[i] = atomicAdd(&lcnt[b], 1);
        } else mybkt[i] = -1;
    }
    __syncthreads();
    if (tid < 128) lbase[tid] = lcnt[tid] ? atomicAdd(&gcur[tid], lcnt[tid]) : 0;
    __syncthreads();
    #pragma unroll
    for (int i = 0; i < 16; ++i) {
        if (mybkt[i] >= 0) {
            int pos = lbase[mybkt[i]] + myrank[i];
            if (pos < BKT_CAP) pairs[(size_t)mybkt[i] * BKT_CAP + pos] = mypair[i];
        }
    }
}

__global__ __launch_bounds__(256) void k_cnt(const unsigned* __restrict__ pairs, const int* __restrict__ gcur,
                                             int* __restrict__ cnt, int n) {
    __shared__ int lcnt[512];
    int b = blockIdx.x, tid = threadIdx.x;
    for (int i = tid; i < 512; i += 256) lcnt[i] = 0;
    __syncthreads();
    int m = gcur[b];
    if (m > BKT_CAP) m = BKT_CAP;
    const unsigned* p = pairs + (size_t)b * BKT_CAP;
    for (int i = tid; i < m; i += 256) atomicAdd(&lcnt[p[i] >> 16], 1);
    __syncthreads();
    int base = b * 512;
    for (int i = tid; i < 512; i += 256) {
        int node = base + i;
        if (node < n) cnt[node] = lcnt[i];
    }
}

// Fused per-1024-window: degree counting-sort -> perm, and 8-padded exclusive
// scan of counts -> part + window total.
__global__ __launch_bounds__(1024) void k_prep_win(const int* __restrict__ cnt, int* __restrict__ perm,
                                                   int* __restrict__ part, int* __restrict__ tots, int n) {
    __shared__ int hist[256];
    __shared__ int hcur[256];
    __shared__ int wtot[16];
    __shared__ int wpre[16];
    int tid  = threadIdx.x;
    int lane = tid & 63;
    int wv   = tid >> 6;
    int base = blockIdx.x * 1024;
    if (tid < 256) hist[tid] = 0;
    __syncthreads();
    int i = base + tid;
    bool act = i < n;
    int c = 0, d = 0, rank = 0;
    if (act) {
        c = cnt[i];
        d = c > 255 ? 255 : c;
        rank = atomicAdd(&hist[d], 1);
    }
    __syncthreads();
    {   // scan hist[256]
        int v = (tid < 256) ? hist[tid] : 0;
        int val = v;
        #pragma unroll
        for (int off = 1; off < 64; off <<= 1) {
            int t = __shfl_up(val, off);
            if (lane >= off) val += t;
        }
        if (lane == 63) wtot[wv] = val;
        __syncthreads();
        if (tid == 0) {
            int s = 0;
            #pragma unroll
            for (int w = 0; w < 4; ++w) { wpre[w] = s; s += wtot[w]; }
        }
        __syncthreads();
        if (tid < 256) hcur[tid] = val - v + wpre[wv];
        __syncthreads();
        if (act) perm[base + hcur[d] + rank] = i;
        __syncthreads();
    }
    {   // padded exclusive scan of ((c+7)&~7)
        int p = act ? ((c + 7) & ~7) : 0;
        int val = p;
        #pragma unroll
        for (int off = 1; off < 64; off <<= 1) {
            int t = __shfl_up(val, off);
            if (lane >= off) val += t;
        }
        if (lane == 63) wtot[wv] = val;
        __syncthreads();
        if (tid == 0) {
            int s = 0;
            #pragma unroll
            for (int w = 0; w < 16; ++w) { wpre[w] = s; s += wtot[w]; }
            tots[blockIdx.x] = s;
        }
        __syncthreads();
        if (act) part[i] = val - p + wpre[wv];
    }
}

__global__ __launch_bounds__(1024) void k_scan_tops(int* __restrict__ tots, int* __restrict__ total_out, int nch) {
    __shared__ int wtot[16];
    __shared__ int wpre[16];
    int tid  = threadIdx.x;
    int lane = tid & 63;
    int wv   = tid >> 6;
    int v    = (tid < nch) ? tots[tid] : 0;
    int val  = v;
    #pragma unroll
    for (int off = 1; off < 64; off <<= 1) {
        int t = __shfl_up(val, off);
        if (lane >= off) val += t;
    }
    if (lane == 63) wtot[wv] = val;
    __syncthreads();
    if (tid == 0) {
        int s = 0;
        #pragma unroll
        for (int w = 0; w < 16; ++w) { wpre[w] = s; s += wtot[w]; }
        *total_out = s;
    }
    __syncthreads();
    int excl = val - v + wpre[wv];
    if (tid < nch) tots[tid] = excl;
}

__global__ __launch_bounds__(1024) void k_scan_add(int* __restrict__ offs, const int* __restrict__ tots, int n) {
    int i = blockIdx.x * 1024 + threadIdx.x;
    if (i < n) offs[i] += tots[blockIdx.x];
}

__global__ __launch_bounds__(256) void k_scatter(const unsigned* __restrict__ pairs, const int* __restrict__ gcur,
                                                 const int* __restrict__ offs, ushort* __restrict__ esrc, int n) {
    __shared__ int lcur[512];
    __shared__ int loffs[512];
    int b = blockIdx.x, tid = threadIdx.x;
    int base = b * 512;
    for (int i = tid; i < 512; i += 256) {
        lcur[i] = 0;
        int node = base + i;
        loffs[i] = (node < n) ? offs[node] : 0;
    }
    __syncthreads();
    int m = gcur[b];
    if (m > BKT_CAP) m = BKT_CAP;
    const unsigned* p = pairs + (size_t)b * BKT_CAP;
    for (int i = tid; i < m; i += 256) {
        unsigned pr = p[i];
        int dlow = pr >> 16;
        int r = atomicAdd(&lcur[dlow], 1);
        esrc[loffs[dlow] + r] = (ushort)(pr & 0xffffu);
    }
}

// ---------------- cast W0|W1|W2 -> bf16 ----------------

__global__ __launch_bounds__(256) void k_cast3(const float* __restrict__ a, int na,
                                               const float* __restrict__ b, int nb,
                                               const float* __restrict__ c, int nc,
                                               ushort* __restrict__ out) {
    int i = blockIdx.x * 256 + threadIdx.x;
    if (i >= na + nb + nc) return;
    float v = (i < na) ? a[i] : ((i < na + nb) ? b[i - na] : c[i - na - nb]);
    out[i] = f2bf(v);
}

// ---------------- GEMM: planes_out[N/32][Mp][32] = X @ Wb^T ----------------

template <typename InT, int N, bool PLANES_IN>
__global__ __launch_bounds__(256) void k_gemm_mfma(const InT* __restrict__ X, const ushort* __restrict__ Wb,
                                                   ushort* __restrict__ Y, int M, int Mp) {
    int w    = threadIdx.x >> 6;
    int lane = threadIdx.x & 63;
    int rowf = blockIdx.x * 64 + w * 16 + (lane & 15);
    int kb   = (lane >> 4) * 8;

    bf16x8 a[4];
    if (rowf < M) {
        #pragma unroll
        for (int ks = 0; ks < 4; ++ks) {
            if constexpr (PLANES_IN) {
                a[ks] = *(const bf16x8*)((const ushort*)X + (size_t)ks * Mp * 32 + (size_t)rowf * 32 + kb);
            } else {
                const float* xp = (const float*)X + (size_t)rowf * 128 + ks * 32 + kb;
                float4 f0 = *(const float4*)xp;
                float4 f1 = *(const float4*)(xp + 4);
                bf16x8 t;
                t[0] = f2bf(f0.x); t[1] = f2bf(f0.y); t[2] = f2bf(f0.z); t[3] = f2bf(f0.w);
                t[4] = f2bf(f1.x); t[5] = f2bf(f1.y); t[6] = f2bf(f1.z); t[7] = f2bf(f1.w);
                a[ks] = t;
            }
        }
    } else {
        #pragma unroll
        for (int ks = 0; ks < 4; ++ks) {
            bf16x8 z = {0, 0, 0, 0, 0, 0, 0, 0};
            a[ks] = z;
        }
    }

    constexpr int NT = N / 16;
    f32x4 acc[NT];
    #pragma unroll
    for (int nt = 0; nt < NT; ++nt) acc[nt] = (f32x4){0.f, 0.f, 0.f, 0.f};

    #pragma unroll
    for (int nt = 0; nt < NT; ++nt) {
        const ushort* wp = Wb + (size_t)(nt * 16 + (lane & 15)) * 128 + kb;
        #pragma unroll
        for (int ks = 0; ks < 4; ++ks) {
            bf16x8 b = *(const bf16x8*)(wp + ks * 32);
            acc[nt] = __builtin_amdgcn_mfma_f32_16x16x32_bf16(a[ks], b, acc[nt], 0, 0, 0);
        }
    }

    int c  = lane & 15;
    int r0 = blockIdx.x * 64 + w * 16 + (lane >> 4) * 4;
    #pragma unroll
    for (int j = 0; j < 4; ++j) {
        int r = r0 + j;
        if (r < M) {
            #pragma unroll
            for (int nt = 0; nt < NT; ++nt)
                Y[(size_t)(nt >> 1) * Mp * 32 + (size_t)r * 32 + (nt & 1) * 16 + c] = (ushort)f2bf(acc[nt][j]);
        }
    }
}

// ---------------- Aggregation ----------------
// Wave = 16 nodes x 4 lanes; lane sub covers a uint4 (8 feats) of the 64B
// plane-row.  Segments 8-aligned + sentinel-padded (idx n -> zero row):
// branchless loop, uint4 idx-block load per 8 edges, one-ahead prefetch.

#define ACC8(T)  { a0 += bflo((T).x); a1 += bfhi((T).x); a2 += bflo((T).y); a3 += bfhi((T).y); \
                   a4 += bflo((T).z); a5 += bfhi((T).z); a6 += bflo((T).w); a7 += bfhi((T).w); }

template <bool RELU>
__global__ __launch_bounds__(256) void k_agg128(const ushort* __restrict__ Yp, const int* __restrict__ offs,
                                                const int* __restrict__ cnt, const ushort* __restrict__ esrc,
                                                const float* __restrict__ bias, ushort* __restrict__ Zp,
                                                const int* __restrict__ perm, int* __restrict__ qh,
                                                int n, int nchunk) {
    __shared__ int sQ, sT;
    if (threadIdx.x == 0) {
        int pref = xcc_id() & 3;
        int t = -1, qsel = 0;
        #pragma unroll
        for (int a = 0; a < 4; ++a) {
            int cand = (pref + a) & 3;
            int tt = atomicAdd(&qh[cand * 16], 1);
            if (tt < nchunk) { qsel = cand; t = tt; break; }
        }
        sQ = qsel; sT = t;
    }
    __syncthreads();
    int q = sQ, t = sT;
    if (t < 0) return;
    int lane = threadIdx.x & 63;
    int wv   = threadIdx.x >> 6;
    int g    = lane >> 2;
    int sub  = lane & 3;
    int idx  = t * CHUNK + wv * 16 + g;
    bool active = idx < n;
    int nd = 0, start = 0, deg = 0;
    if (active) {
        nd    = perm[idx];
        start = offs[nd];
        deg   = cnt[nd];
    }
    const uint4* Y4 = (const uint4*)(Yp + (size_t)q * (n + 1) * 32);
    uint4*       Z4 = (uint4*)(Zp + (size_t)q * (n + 1) * 32);

    float a0 = 0.f, a1 = 0.f, a2 = 0.f, a3 = 0.f, a4 = 0.f, a5 = 0.f, a6 = 0.f, a7 = 0.f;

    int nblk = active ? ((deg + 7) >> 3) : 0;
    const uint4* ep = (const uint4*)(esrc + start);   // 16B-aligned (8-aligned start)
    uint4 ib = ep[0];
    #pragma unroll 2
    for (int b = 0; b < nblk; ++b) {
        uint4 ibn = ep[b + 1];                        // one-ahead prefetch (padded)
        unsigned s0 = ib.x & 0xffffu, s1 = ib.x >> 16;
        unsigned s2 = ib.y & 0xffffu, s3 = ib.y >> 16;
        unsigned s4 = ib.z & 0xffffu, s5 = ib.z >> 16;
        unsigned s6 = ib.w & 0xffffu, s7 = ib.w >> 16;
        uint4 t0 = Y4[(size_t)s0 * 4 + sub];
        uint4 t1 = Y4[(size_t)s1 * 4 + sub];
        uint4 t2 = Y4[(size_t)s2 * 4 + sub];
        uint4 t3 = Y4[(size_t)s3 * 4 + sub];
        uint4 t4 = Y4[(size_t)s4 * 4 + sub];
        uint4 t5 = Y4[(size_t)s5 * 4 + sub];
        uint4 t6 = Y4[(size_t)s6 * 4 + sub];
        uint4 t7 = Y4[(size_t)s7 * 4 + sub];
        ACC8(t0); ACC8(t1); ACC8(t2); ACC8(t3); ACC8(t4); ACC8(t5); ACC8(t6); ACC8(t7);
        ib = ibn;
    }

    if (active) {
        float scale = 1.0f / (float)(deg + 2);
        uint4 sf = Y4[(size_t)nd * 4 + sub];
        int f0 = q * 32 + sub * 8;
        float4 bA = *(const float4*)&bias[f0];
        float4 bB = *(const float4*)&bias[f0 + 4];
        float r0 = (a0 + 2.f * bflo(sf.x)) * scale + bA.x;
        float r1 = (a1 + 2.f * bfhi(sf.x)) * scale + bA.y;
        float r2 = (a2 + 2.f * bflo(sf.y)) * scale + bA.z;
        float r3 = (a3 + 2.f * bfhi(sf.y)) * scale + bA.w;
        float r4 = (a4 + 2.f * bflo(sf.z)) * scale + bB.x;
        float r5 = (a5 + 2.f * bfhi(sf.z)) * scale + bB.y;
        float r6 = (a6 + 2.f * bflo(sf.w)) * scale + bB.z;
        float r7 = (a7 + 2.f * bfhi(sf.w)) * scale + bB.w;
        if (RELU) {
            r0 = fmaxf(r0, 0.f); r1 = fmaxf(r1, 0.f); r2 = fmaxf(r2, 0.f); r3 = fmaxf(r3, 0.f);
            r4 = fmaxf(r4, 0.f); r5 = fmaxf(r5, 0.f); r6 = fmaxf(r6, 0.f); r7 = fmaxf(r7, 0.f);
        }
        uint4 o;
        o.x = (unsigned)f2bf(r0) | ((unsigned)f2bf(r1) << 16);
        o.y = (unsigned)f2bf(r2) | ((unsigned)f2bf(r3) << 16);
        o.z = (unsigned)f2bf(r4) | ((unsigned)f2bf(r5) << 16);
        o.w = (unsigned)f2bf(r6) | ((unsigned)f2bf(r7) << 16);
        Z4[(size_t)nd * 4 + sub] = o;
    }
}

// Layer-2: 2 half planes [(2)][(n+1)][32f], fp32 canonical [n][64] output.
__global__ __launch_bounds__(256) void k_agg64(const ushort* __restrict__ Yp, const int* __restrict__ offs,
                                               const int* __restrict__ cnt, const ushort* __restrict__ esrc,
                                               const float* __restrict__ bias, float* __restrict__ Z,
                                               const int* __restrict__ perm, int* __restrict__ qh,
                                               int n, int nchunk) {
    __shared__ int sQ, sT;
    if (threadIdx.x == 0) {
        int pref = xcc_id() & 1;
        int t = -1, qsel = 0;
        #pragma unroll
        for (int a = 0; a < 2; ++a) {
            int cand = (pref + a) & 1;
            int tt = atomicAdd(&qh[cand * 16], 1);
            if (tt < nchunk) { qsel = cand; t = tt; break; }
        }
        sQ = qsel; sT = t;
    }
    __syncthreads();
    int h = sQ, t = sT;
    if (t < 0) return;
    int lane = threadIdx.x & 63;
    int wv   = threadIdx.x >> 6;
    int g    = lane >> 2;
    int sub  = lane & 3;
    int idx  = t * CHUNK + wv * 16 + g;
    bool active = idx < n;
    int nd = 0, start = 0, deg = 0;
    if (active) {
        nd    = perm[idx];
        start = offs[nd];
        deg   = cnt[nd];
    }
    const uint4* Y4 = (const uint4*)(Yp + (size_t)h * (n + 1) * 32);

    float a0 = 0.f, a1 = 0.f, a2 = 0.f, a3 = 0.f, a4 = 0.f, a5 = 0.f, a6 = 0.f, a7 = 0.f;

    int nblk = active ? ((deg + 7) >> 3) : 0;
    const uint4* ep = (const uint4*)(esrc + start);
    uint4 ib = ep[0];
    #pragma unroll 2
    for (int b = 0; b < nblk; ++b) {
        uint4 ibn = ep[b + 1];
        unsigned s0 = ib.x & 0xffffu, s1 = ib.x >> 16;
        unsigned s2 = ib.y & 0xffffu, s3 = ib.y >> 16;
        unsigned s4 = ib.z & 0xffffu, s5 = ib.z >> 16;
        unsigned s6 = ib.w & 0xffffu, s7 = ib.w >> 16;
        uint4 t0 = Y4[(size_t)s0 * 4 + sub];
        uint4 t1 = Y4[(size_t)s1 * 4 + sub];
        uint4 t2 = Y4[(size_t)s2 * 4 + sub];
        uint4 t3 = Y4[(size_t)s3 * 4 + sub];
        uint4 t4 = Y4[(size_t)s4 * 4 + sub];
        uint4 t5 = Y4[(size_t)s5 * 4 + sub];
        uint4 t6 = Y4[(size_t)s6 * 4 + sub];
        uint4 t7 = Y4[(size_t)s7 * 4 + sub];
        ACC8(t0); ACC8(t1); ACC8(t2); ACC8(t3); ACC8(t4); ACC8(t5); ACC8(t6); ACC8(t7);
        ib = ibn;
    }

    if (active) {
        float scale = 1.0f / (float)(deg + 2);
        uint4 sf = Y4[(size_t)nd * 4 + sub];
        int f0 = h * 32 + sub * 8;
        float4 bA = *(const float4*)&bias[f0];
        float4 bB = *(const float4*)&bias[f0 + 4];
        float4 oA, oB;
        oA.x = (a0 + 2.f * bflo(sf.x)) * scale + bA.x;
        oA.y = (a1 + 2.f * bfhi(sf.x)) * scale + bA.y;
        oA.z = (a2 + 2.f * bflo(sf.y)) * scale + bA.z;
        oA.w = (a3 + 2.f * bfhi(sf.y)) * scale + bA.w;
        oB.x = (a4 + 2.f * bflo(sf.z)) * scale + bB.x;
        oB.y = (a5 + 2.f * bfhi(sf.z)) * scale + bB.y;
        oB.z = (a6 + 2.f * bflo(sf.w)) * scale + bB.z;
        oB.w = (a7 + 2.f * bfhi(sf.w)) * scale + bB.w;
        float* zr = Z + (size_t)nd * 64 + f0;
        *(float4*)zr       = oA;
        *(float4*)(zr + 4) = oB;
    }
}

// ---------------- launch ----------------

extern "C" void kernel_launch(void* const* d_in, const int* in_sizes, int n_in,
                              void* d_out, int out_size, void* d_ws, size_t ws_size,
                              hipStream_t stream) {
    const float* in_feat = (const float*)d_in[0];
    const int*   src     = (const int*)d_in[1];
    const int*   dst     = (const int*)d_in[2];
    const float* W0      = (const float*)d_in[3];
    const float* b0      = (const float*)d_in[4];
    const float* W1      = (const float*)d_in[5];
    const float* b1      = (const float*)d_in[6];
    const float* W2      = (const float*)d_in[7];
    const float* b2      = (const float*)d_in[8];
    float* out = (float*)d_out;

    const int n  = in_sizes[0] / NFEAT;   // 50000 (<= 65535 assumed)
    const int ne = in_sizes[1];           // 800000
    const int nch = (n + 1023) / 1024;
    const int NB  = (n + 511) >> 9;
    const int nchunk = (n + CHUNK - 1) / CHUNK;
    const int escap = (ne + 8 * n + 31) & ~15;   // padded esrc capacity (ushorts)

    // workspace carve (16B aligned)
    int* offs       = (int*)d_ws;                          // n+1
    int* tots       = offs + (((n + 1) + 3) & ~3);         // 1024
    int* gcur       = tots + 1024;                         // 128  } ctl: 320 ints
    int* qh         = gcur + 128;                          // 192  }
    int* cnt        = qh + 192;                            // n
    int* perm       = cnt + ((n + 3) & ~3);                // n
    unsigned* pairs = (unsigned*)(perm + ((n + 3) & ~3));  // 128*BKT_CAP
    ushort* esrc    = (ushort*)(pairs + (size_t)128 * BKT_CAP);  // escap
    ushort* Wb      = esrc + escap;                        // 40960
    ushort* Ybuf    = Wb + 40960;                          // (n+1)*128 plane-major
    ushort* Zbuf    = Ybuf + (size_t)(n + 1) * NFEAT;      // (n+1)*128 plane-major

    // --- init (ctl zeros + esrc sentinel fill + Ybuf sentinel rows) ---
    const int fillN = escap / 2;                           // uints
    const unsigned sent2 = ((unsigned)n << 16) | (unsigned)n;
    k_init<<<(fillN + 320 + 64 + 255) / 256, 256, 0, stream>>>((unsigned*)esrc, fillN, sent2, gcur, Ybuf, n);

    // --- CSR build (8-aligned segments) + windowed sort ---
    k_bin<<<(ne + 4095) / 4096, 256, 0, stream>>>(src, dst, gcur, pairs, ne);
    k_cnt<<<NB, 256, 0, stream>>>(pairs, gcur, cnt, n);
    k_prep_win<<<nch, 1024, 0, stream>>>(cnt, perm, offs, tots, n);
    k_scan_tops<<<1, 1024, 0, stream>>>(tots, offs + n, nch);
    k_scan_add<<<nch, 1024, 0, stream>>>(offs, tots, n);
    k_scatter<<<NB, 256, 0, stream>>>(pairs, gcur, offs, esrc, n);

    // --- weights -> bf16 ---
    k_cast3<<<(40960 + 255) / 256, 256, 0, stream>>>(W0, 16384, W1, 16384, W2, 8192, Wb);
    const ushort* Wb0 = Wb;
    const ushort* Wb1 = Wb + 16384;
    const ushort* Wb2 = Wb + 32768;

    const int gg = (n + 63) / 64;
    const int Mp = n + 1;

    // --- layer 0 ---
    k_gemm_mfma<float, 128, false><<<gg, 256, 0, stream>>>(in_feat, Wb0, Ybuf, n, Mp);
    k_agg128<true><<<4 * nchunk, 256, 0, stream>>>(Ybuf, offs, cnt, esrc, b0, Zbuf, perm, qh, n, nchunk);
    // --- layer 1 ---
    k_gemm_mfma<ushort, 128, true><<<gg, 256, 0, stream>>>(Zbuf, Wb1, Ybuf, n, Mp);
    k_agg128<true><<<4 * nchunk, 256, 0, stream>>>(Ybuf, offs, cnt, esrc, b1, Zbuf, perm, qh + 64, n, nchunk);
    // --- layer 2 (N=64, no relu, fp32 out) ---
    k_gemm_mfma<ushort, 64, true><<<gg, 256, 0, stream>>>(Zbuf, Wb2, Ybuf, n, Mp);
    k_agg64<<<2 * nchunk, 256, 0, stream>>>(Ybuf, offs, cnt, esrc, b2, out, perm, qh + 128, n, nchunk);

    (void)ws_size; (void)n_in; (void)out_size;
}

// Round 11
// 200.022 us; speedup vs baseline: 1.6431x; 1.1059x over previous
//
#include <hip/hip_runtime.h>
#include <hip/hip_bf16.h>

// ---------------------------------------------------------------------------
// SAGE-GCN x3 on MI355X.  Round 11.
//   Launch-count reduction (r10 was flat; est. 30-45us of graph gaps over 14
//   kernels): CSR cnt+sort+scan fused into k_cntprep with atomic window base
//   (2 scan kernels dropped); weight cast folded into k_init.  14 -> 10.
//   GEMM: 128 rows/block, 2 row-sets per wave sharing B frags (halves W
//   re-reads).  Agg: unchanged r10 structure (XCC quarter planes, uint4
//   gathers, windowed sort, sentinel-padded branchless loop).
// ---------------------------------------------------------------------------

#define NFEAT 128
#define BKT_CAP 12288
#define CHUNK 64

using bf16x8 = __attribute__((ext_vector_type(8))) short;
using f32x4  = __attribute__((ext_vector_type(4))) float;

__device__ __forceinline__ ushort f2bf(float f) {
    unsigned u = __float_as_uint(f);
    u = (u + 0x7fffu + ((u >> 16) & 1u)) >> 16;
    return (ushort)u;
}
__device__ __forceinline__ float bflo(unsigned v) { return __uint_as_float(v << 16); }
__device__ __forceinline__ float bfhi(unsigned v) { return __uint_as_float(v & 0xffff0000u); }

__device__ __forceinline__ int xcc_id() {
    int x;
    asm volatile("s_getreg_b32 %0, hwreg(HW_REG_XCC_ID)" : "=s"(x));
    return x & 7;
}

// ---------------- init: esrc sentinel fill + ctl zeros + plane sentinel rows
//                  + W0|W1|W2 -> bf16 cast (fused) ----------------

__global__ __launch_bounds__(256) void k_init(unsigned* __restrict__ esrc_u32, int fillN, unsigned sent2,
                                              int* __restrict__ ctl, ushort* __restrict__ Ybuf, int n,
                                              const float* __restrict__ W0, const float* __restrict__ W1,
                                              const float* __restrict__ W2, ushort* __restrict__ Wb) {
    int i = blockIdx.x * 256 + threadIdx.x;
    if (i < fillN) {
        esrc_u32[i] = sent2;
    } else if (i < fillN + 336) {
        ctl[i - fillN] = 0;
    } else if (i < fillN + 336 + 64) {
        int j = i - fillN - 336;      // 4 planes x 16 uints (64B sentinel row)
        int p = j >> 4, k = j & 15;
        ((unsigned*)(Ybuf + (size_t)p * (n + 1) * 32 + (size_t)n * 32))[k] = 0u;
    } else if (i < fillN + 336 + 64 + 40960) {
        int j = i - fillN - 336 - 64;
        float v = (j < 16384) ? W0[j] : ((j < 32768) ? W1[j - 16384] : W2[j - 32768]);
        Wb[j] = f2bf(v);
    }
}

// ---------------- CSR pass A: bin edges into 512-node buckets ----------------

__global__ __launch_bounds__(256) void k_bin(const int* __restrict__ src, const int* __restrict__ dst,
                                             int* __restrict__ gcur, unsigned* __restrict__ pairs, int ne) {
    __shared__ int lcnt[128];
    __shared__ int lbase[128];
    int tid = threadIdx.x;
    if (tid < 128) lcnt[tid] = 0;
    __syncthreads();
    int e0 = blockIdx.x * 4096;
    int myrank[16];
    int mybkt[16];
    unsigned mypair[16];
    #pragma unroll
    for (int i = 0; i < 16; ++i) {
        int e = e0 + tid + i * 256;
        if (e < ne) {
            int s = src[e], d = dst[e];
            int b = d >> 9;
            mybkt[i]  = b;
            mypair[i] = (unsigned)(s & 0xffff) | ((unsigned)(d & 511) << 16);
            myrank[i] = atomicAdd(&lcnt[b], 1);
        } else mybkt[i] = -1;
    }
    __syncthreads();
    if (tid < 128) lbase[tid] = lcnt[tid] ? atomicAdd(&gcur[tid], lcnt[tid]) : 0;
    __syncthreads();
    #pragma unroll
    for (int i = 0; i < 16; ++i) {
        if (mybkt[i] >= 0) {
            int pos = lbase[mybkt[i]] + myrank[i];
            if (pos < BKT_CAP) pairs[(size_t)mybkt[i] * BKT_CAP + pos] = mypair[i];
        }
    }
}

// ---------------- fused: per-1024-window count + degree-sort + padded scan ----------------
// One block = 2 buckets (1024 nodes).  Counts from pairs (LDS), writes cnt,
// counting-sorts node ids by degree -> perm, 8-padded exclusive scan of
// degrees with ATOMIC global base -> offs (segment starts, 8-aligned).

__global__ __launch_bounds__(1024) void k_cntprep(const unsigned* __restrict__ pairs, const int* __restrict__ gcur,
                                                  int* __restrict__ cnt, int* __restrict__ perm,
                                                  int* __restrict__ offs, int* __restrict__ gbase, int n) {
    __shared__ int lcnt[1024];
    __shared__ int hist[256];
    __shared__ int hcur[256];
    __shared__ int wtot[16];
    __shared__ int wpre[16];
    __shared__ int sbase;
    int tid  = threadIdx.x;
    int lane = tid & 63;
    int wv   = tid >> 6;
    int base = blockIdx.x * 1024;
    lcnt[tid] = 0;
    if (tid < 256) hist[tid] = 0;
    __syncthreads();
    #pragma unroll
    for (int h = 0; h < 2; ++h) {
        int bkt = blockIdx.x * 2 + h;
        int m = gcur[bkt];
        if (m > BKT_CAP) m = BKT_CAP;
        const unsigned* p = pairs + (size_t)bkt * BKT_CAP;
        for (int i = tid; i < m; i += 1024)
            atomicAdd(&lcnt[(int)(p[i] >> 16) + h * 512], 1);
    }
    __syncthreads();
    int i   = base + tid;
    bool act = i < n;
    int c = act ? lcnt[tid] : 0;
    if (act) cnt[i] = c;
    int d = c > 255 ? 255 : c;
    int rank = 0;
    if (act) rank = atomicAdd(&hist[d], 1);
    __syncthreads();
    {   // exclusive scan of hist[256] -> hcur; perm
        int v = (tid < 256) ? hist[tid] : 0;
        int val = v;
        #pragma unroll
        for (int off = 1; off < 64; off <<= 1) {
            int t = __shfl_up(val, off);
            if (lane >= off) val += t;
        }
        if (lane == 63) wtot[wv] = val;
        __syncthreads();
        if (tid == 0) {
            int s = 0;
            #pragma unroll
            for (int w = 0; w < 4; ++w) { wpre[w] = s; s += wtot[w]; }
        }
        __syncthreads();
        if (tid < 256) hcur[tid] = val - v + wpre[wv];
        __syncthreads();
        if (act) perm[base + hcur[d] + rank] = i;
        __syncthreads();
    }
    {   // 8-padded exclusive scan + atomic global base -> offs
        int p8 = act ? ((c + 7) & ~7) : 0;
        int val = p8;
        #pragma unroll
        for (int off = 1; off < 64; off <<= 1) {
            int t = __shfl_up(val, off);
            if (lane >= off) val += t;
        }
        if (lane == 63) wtot[wv] = val;
        __syncthreads();
        if (tid == 0) {
            int s = 0;
            #pragma unroll
            for (int w = 0; w < 16; ++w) { wpre[w] = s; s += wtot[w]; }
            sbase = atomicAdd(gbase, s);
        }
        __syncthreads();
        if (act) offs[i] = sbase + val - p8 + wpre[wv];
    }
}

// ---------------- CSR pass B: per-bucket scatter into esrc ----------------

__global__ __launch_bounds__(256) void k_scatter(const unsigned* __restrict__ pairs, const int* __restrict__ gcur,
                                                 const int* __restrict__ offs, ushort* __restrict__ esrc, int n) {
    __shared__ int lcur[512];
    __shared__ int loffs[512];
    int b = blockIdx.x, tid = threadIdx.x;
    int base = b * 512;
    for (int i = tid; i < 512; i += 256) {
        lcur[i] = 0;
        int node = base + i;
        loffs[i] = (node < n) ? offs[node] : 0;
    }
    __syncthreads();
    int m = gcur[b];
    if (m > BKT_CAP) m = BKT_CAP;
    const unsigned* p = pairs + (size_t)b * BKT_CAP;
    for (int i = tid; i < m; i += 256) {
        unsigned pr = p[i];
        int dlow = pr >> 16;
        int r = atomicAdd(&lcur[dlow], 1);
        esrc[loffs[dlow] + r] = (ushort)(pr & 0xffffu);
    }
}

// ---------------- GEMM: planes_out[N/32][Mp][32] = X @ Wb^T ----------------
// 128 rows/block: each wave owns 2 row-sets of 16, sharing B frags.

template <typename InT, int N, bool PLANES_IN>
__global__ __launch_bounds__(256) void k_gemm_mfma(const InT* __restrict__ X, const ushort* __restrict__ Wb,
                                                   ushort* __restrict__ Y, int M, int Mp) {
    int w    = threadIdx.x >> 6;
    int lane = threadIdx.x & 63;
    int kb   = (lane >> 4) * 8;
    int rbase = blockIdx.x * 128 + w * 16 + (lane & 15);

    bf16x8 a0[4], a1[4];
    #pragma unroll
    for (int set = 0; set < 2; ++set) {
        int rowf = rbase + set * 64;
        bf16x8* a = set ? a1 : a0;
        if (rowf < M) {
            #pragma unroll
            for (int ks = 0; ks < 4; ++ks) {
                if constexpr (PLANES_IN) {
                    a[ks] = *(const bf16x8*)((const ushort*)X + (size_t)ks * Mp * 32 + (size_t)rowf * 32 + kb);
                } else {
                    const float* xp = (const float*)X + (size_t)rowf * 128 + ks * 32 + kb;
                    float4 f0 = *(const float4*)xp;
                    float4 f1 = *(const float4*)(xp + 4);
                    bf16x8 t;
                    t[0] = f2bf(f0.x); t[1] = f2bf(f0.y); t[2] = f2bf(f0.z); t[3] = f2bf(f0.w);
                    t[4] = f2bf(f1.x); t[5] = f2bf(f1.y); t[6] = f2bf(f1.z); t[7] = f2bf(f1.w);
                    a[ks] = t;
                }
            }
        } else {
            #pragma unroll
            for (int ks = 0; ks < 4; ++ks) {
                bf16x8 z = {0, 0, 0, 0, 0, 0, 0, 0};
                a[ks] = z;
            }
        }
    }

    constexpr int NT = N / 16;
    f32x4 acc0[NT], acc1[NT];
    #pragma unroll
    for (int nt = 0; nt < NT; ++nt) {
        acc0[nt] = (f32x4){0.f, 0.f, 0.f, 0.f};
        acc1[nt] = (f32x4){0.f, 0.f, 0.f, 0.f};
    }

    #pragma unroll
    for (int nt = 0; nt < NT; ++nt) {
        const ushort* wp = Wb + (size_t)(nt * 16 + (lane & 15)) * 128 + kb;
        #pragma unroll
        for (int ks = 0; ks < 4; ++ks) {
            bf16x8 b = *(const bf16x8*)(wp + ks * 32);
            acc0[nt] = __builtin_amdgcn_mfma_f32_16x16x32_bf16(a0[ks], b, acc0[nt], 0, 0, 0);
            acc1[nt] = __builtin_amdgcn_mfma_f32_16x16x32_bf16(a1[ks], b, acc1[nt], 0, 0, 0);
        }
    }

    int c  = lane & 15;
    int rr = blockIdx.x * 128 + w * 16 + (lane >> 4) * 4;
    #pragma unroll
    for (int set = 0; set < 2; ++set) {
        f32x4* acc = set ? acc1 : acc0;
        #pragma unroll
        for (int j = 0; j < 4; ++j) {
            int r = rr + set * 64 + j;
            if (r < M) {
                #pragma unroll
                for (int nt = 0; nt < NT; ++nt)
                    Y[(size_t)(nt >> 1) * Mp * 32 + (size_t)r * 32 + (nt & 1) * 16 + c] = (ushort)f2bf(acc[nt][j]);
            }
        }
    }
}

// ---------------- Aggregation (r10 structure) ----------------

#define ACC8(T)  { a0 += bflo((T).x); a1 += bfhi((T).x); a2 += bflo((T).y); a3 += bfhi((T).y); \
                   a4 += bflo((T).z); a5 += bfhi((T).z); a6 += bflo((T).w); a7 += bfhi((T).w); }

template <bool RELU>
__global__ __launch_bounds__(256) void k_agg128(const ushort* __restrict__ Yp, const int* __restrict__ offs,
                                                const int* __restrict__ cnt, const ushort* __restrict__ esrc,
                                                const float* __restrict__ bias, ushort* __restrict__ Zp,
                                                const int* __restrict__ perm, int* __restrict__ qh,
                                                int n, int nchunk) {
    __shared__ int sQ, sT;
    if (threadIdx.x == 0) {
        int pref = xcc_id() & 3;
        int t = -1, qsel = 0;
        #pragma unroll
        for (int a = 0; a < 4; ++a) {
            int cand = (pref + a) & 3;
            int tt = atomicAdd(&qh[cand * 16], 1);
            if (tt < nchunk) { qsel = cand; t = tt; break; }
        }
        sQ = qsel; sT = t;
    }
    __syncthreads();
    int q = sQ, t = sT;
    if (t < 0) return;
    int lane = threadIdx.x & 63;
    int wv   = threadIdx.x >> 6;
    int g    = lane >> 2;
    int sub  = lane & 3;
    int idx  = t * CHUNK + wv * 16 + g;
    bool active = idx < n;
    int nd = 0, start = 0, deg = 0;
    if (active) {
        nd    = perm[idx];
        start = offs[nd];
        deg   = cnt[nd];
    }
    const uint4* Y4 = (const uint4*)(Yp + (size_t)q * (n + 1) * 32);
    uint4*       Z4 = (uint4*)(Zp + (size_t)q * (n + 1) * 32);

    float a0 = 0.f, a1 = 0.f, a2 = 0.f, a3 = 0.f, a4 = 0.f, a5 = 0.f, a6 = 0.f, a7 = 0.f;

    int nblk = active ? ((deg + 7) >> 3) : 0;
    const uint4* ep = (const uint4*)(esrc + start);
    uint4 ib = ep[0];
    #pragma unroll 2
    for (int b = 0; b < nblk; ++b) {
        uint4 ibn = ep[b + 1];
        unsigned s0 = ib.x & 0xffffu, s1 = ib.x >> 16;
        unsigned s2 = ib.y & 0xffffu, s3 = ib.y >> 16;
        unsigned s4 = ib.z & 0xffffu, s5 = ib.z >> 16;
        unsigned s6 = ib.w & 0xffffu, s7 = ib.w >> 16;
        uint4 t0 = Y4[(size_t)s0 * 4 + sub];
        uint4 t1 = Y4[(size_t)s1 * 4 + sub];
        uint4 t2 = Y4[(size_t)s2 * 4 + sub];
        uint4 t3 = Y4[(size_t)s3 * 4 + sub];
        uint4 t4 = Y4[(size_t)s4 * 4 + sub];
        uint4 t5 = Y4[(size_t)s5 * 4 + sub];
        uint4 t6 = Y4[(size_t)s6 * 4 + sub];
        uint4 t7 = Y4[(size_t)s7 * 4 + sub];
        ACC8(t0); ACC8(t1); ACC8(t2); ACC8(t3); ACC8(t4); ACC8(t5); ACC8(t6); ACC8(t7);
        ib = ibn;
    }

    if (active) {
        float scale = 1.0f / (float)(deg + 2);
        uint4 sf = Y4[(size_t)nd * 4 + sub];
        int f0 = q * 32 + sub * 8;
        float4 bA = *(const float4*)&bias[f0];
        float4 bB = *(const float4*)&bias[f0 + 4];
        float r0 = (a0 + 2.f * bflo(sf.x)) * scale + bA.x;
        float r1 = (a1 + 2.f * bfhi(sf.x)) * scale + bA.y;
        float r2 = (a2 + 2.f * bflo(sf.y)) * scale + bA.z;
        float r3 = (a3 + 2.f * bfhi(sf.y)) * scale + bA.w;
        float r4 = (a4 + 2.f * bflo(sf.z)) * scale + bB.x;
        float r5 = (a5 + 2.f * bfhi(sf.z)) * scale + bB.y;
        float r6 = (a6 + 2.f * bflo(sf.w)) * scale + bB.z;
        float r7 = (a7 + 2.f * bfhi(sf.w)) * scale + bB.w;
        if (RELU) {
            r0 = fmaxf(r0, 0.f); r1 = fmaxf(r1, 0.f); r2 = fmaxf(r2, 0.f); r3 = fmaxf(r3, 0.f);
            r4 = fmaxf(r4, 0.f); r5 = fmaxf(r5, 0.f); r6 = fmaxf(r6, 0.f); r7 = fmaxf(r7, 0.f);
        }
        uint4 o;
        o.x = (unsigned)f2bf(r0) | ((unsigned)f2bf(r1) << 16);
        o.y = (unsigned)f2bf(r2) | ((unsigned)f2bf(r3) << 16);
        o.z = (unsigned)f2bf(r4) | ((unsigned)f2bf(r5) << 16);
        o.w = (unsigned)f2bf(r6) | ((unsigned)f2bf(r7) << 16);
        Z4[(size_t)nd * 4 + sub] = o;
    }
}

__global__ __launch_bounds__(256) void k_agg64(const ushort* __restrict__ Yp, const int* __restrict__ offs,
                                               const int* __restrict__ cnt, const ushort* __restrict__ esrc,
                                               const float* __restrict__ bias, float* __restrict__ Z,
                                               const int* __restrict__ perm, int* __restrict__ qh,
                                               int n, int nchunk) {
    __shared__ int sQ, sT;
    if (threadIdx.x == 0) {
        int pref = xcc_id() & 1;
        int t = -1, qsel = 0;
        #pragma unroll
        for (int a = 0; a < 2; ++a) {
            int cand = (pref + a) & 1;
            int tt = atomicAdd(&qh[cand * 16], 1);
            if (tt < nchunk) { qsel = cand; t = tt; break; }
        }
        sQ = qsel; sT = t;
    }
    __syncthreads();
    int h = sQ, t = sT;
    if (t < 0) return;
    int lane = threadIdx.x & 63;
    int wv   = threadIdx.x >> 6;
    int g    = lane >> 2;
    int sub  = lane & 3;
    int idx  = t * CHUNK + wv * 16 + g;
    bool active = idx < n;
    int nd = 0, start = 0, deg = 0;
    if (active) {
        nd    = perm[idx];
        start = offs[nd];
        deg   = cnt[nd];
    }
    const uint4* Y4 = (const uint4*)(Yp + (size_t)h * (n + 1) * 32);

    float a0 = 0.f, a1 = 0.f, a2 = 0.f, a3 = 0.f, a4 = 0.f, a5 = 0.f, a6 = 0.f, a7 = 0.f;

    int nblk = active ? ((deg + 7) >> 3) : 0;
    const uint4* ep = (const uint4*)(esrc + start);
    uint4 ib = ep[0];
    #pragma unroll 2
    for (int b = 0; b < nblk; ++b) {
        uint4 ibn = ep[b + 1];
        unsigned s0 = ib.x & 0xffffu, s1 = ib.x >> 16;
        unsigned s2 = ib.y & 0xffffu, s3 = ib.y >> 16;
        unsigned s4 = ib.z & 0xffffu, s5 = ib.z >> 16;
        unsigned s6 = ib.w & 0xffffu, s7 = ib.w >> 16;
        uint4 t0 = Y4[(size_t)s0 * 4 + sub];
        uint4 t1 = Y4[(size_t)s1 * 4 + sub];
        uint4 t2 = Y4[(size_t)s2 * 4 + sub];
        uint4 t3 = Y4[(size_t)s3 * 4 + sub];
        uint4 t4 = Y4[(size_t)s4 * 4 + sub];
        uint4 t5 = Y4[(size_t)s5 * 4 + sub];
        uint4 t6 = Y4[(size_t)s6 * 4 + sub];
        uint4 t7 = Y4[(size_t)s7 * 4 + sub];
        ACC8(t0); ACC8(t1); ACC8(t2); ACC8(t3); ACC8(t4); ACC8(t5); ACC8(t6); ACC8(t7);
        ib = ibn;
    }

    if (active) {
        float scale = 1.0f / (float)(deg + 2);
        uint4 sf = Y4[(size_t)nd * 4 + sub];
        int f0 = h * 32 + sub * 8;
        float4 bA = *(const float4*)&bias[f0];
        float4 bB = *(const float4*)&bias[f0 + 4];
        float4 oA, oB;
        oA.x = (a0 + 2.f * bflo(sf.x)) * scale + bA.x;
        oA.y = (a1 + 2.f * bfhi(sf.x)) * scale + bA.y;
        oA.z = (a2 + 2.f * bflo(sf.y)) * scale + bA.z;
        oA.w = (a3 + 2.f * bfhi(sf.y)) * scale + bA.w;
        oB.x = (a4 + 2.f * bflo(sf.z)) * scale + bB.x;
        oB.y = (a5 + 2.f * bfhi(sf.z)) * scale + bB.y;
        oB.z = (a6 + 2.f * bflo(sf.w)) * scale + bB.z;
        oB.w = (a7 + 2.f * bfhi(sf.w)) * scale + bB.w;
        float* zr = Z + (size_t)nd * 64 + f0;
        *(float4*)zr       = oA;
        *(float4*)(zr + 4) = oB;
    }
}

// ---------------- launch ----------------

extern "C" void kernel_launch(void* const* d_in, const int* in_sizes, int n_in,
                              void* d_out, int out_size, void* d_ws, size_t ws_size,
                              hipStream_t stream) {
    const float* in_feat = (const float*)d_in[0];
    const int*   src     = (const int*)d_in[1];
    const int*   dst     = (const int*)d_in[2];
    const float* W0      = (const float*)d_in[3];
    const float* b0      = (const float*)d_in[4];
    const float* W1      = (const float*)d_in[5];
    const float* b1      = (const float*)d_in[6];
    const float* W2      = (const float*)d_in[7];
    const float* b2      = (const float*)d_in[8];
    float* out = (float*)d_out;

    const int n  = in_sizes[0] / NFEAT;   // 50000 (<= 65535 assumed)
    const int ne = in_sizes[1];           // 800000
    const int nch = (n + 1023) / 1024;    // 49 windows (2 buckets each)
    const int NB  = (n + 511) >> 9;       // 98 buckets
    const int nchunk = (n + CHUNK - 1) / CHUNK;
    const int escap = (ne + 8 * n + 31) & ~15;   // padded esrc capacity (ushorts)

    // workspace carve (16B aligned)
    int* offs       = (int*)d_ws;                          // n (+pad)
    int* gcur       = offs + ((n + 4) & ~3);               // 128 } ctl: 336 ints
    int* qh         = gcur + 128;                          // 192 }
    int* gbase      = qh + 192;                            // 16  }
    int* cnt        = gbase + 16;                          // n
    int* perm       = cnt + ((n + 3) & ~3);                // n
    unsigned* pairs = (unsigned*)(perm + ((n + 3) & ~3));  // 128*BKT_CAP
    ushort* esrc    = (ushort*)(pairs + (size_t)128 * BKT_CAP);  // escap
    ushort* Wb      = esrc + escap;                        // 40960
    ushort* Ybuf    = Wb + 40960;                          // (n+1)*128 plane-major
    ushort* Zbuf    = Ybuf + (size_t)(n + 1) * NFEAT;      // (n+1)*128 plane-major

    // --- init (esrc sentinels + ctl zeros + Ybuf sentinel rows + W cast) ---
    const int fillN = escap / 2;                           // uints
    const unsigned sent2 = ((unsigned)n << 16) | (unsigned)n;
    const int initN = fillN + 336 + 64 + 40960;
    k_init<<<(initN + 255) / 256, 256, 0, stream>>>((unsigned*)esrc, fillN, sent2, gcur, Ybuf, n,
                                                    W0, W1, W2, Wb);

    // --- CSR build (8-aligned segments, atomic window base) ---
    k_bin<<<(ne + 4095) / 4096, 256, 0, stream>>>(src, dst, gcur, pairs, ne);
    k_cntprep<<<nch, 1024, 0, stream>>>(pairs, gcur, cnt, perm, offs, gbase, n);
    k_scatter<<<NB, 256, 0, stream>>>(pairs, gcur, offs, esrc, n);

    const ushort* Wb0 = Wb;
    const ushort* Wb1 = Wb + 16384;
    const ushort* Wb2 = Wb + 32768;

    const int gg = (n + 127) / 128;
    const int Mp = n + 1;

    // --- layer 0 ---
    k_gemm_mfma<float, 128, false><<<gg, 256, 0, stream>>>(in_feat, Wb0, Ybuf, n, Mp);
    k_agg128<true><<<4 * nchunk, 256, 0, stream>>>(Ybuf, offs, cnt, esrc, b0, Zbuf, perm, qh, n, nchunk);
    // --- layer 1 ---
    k_gemm_mfma<ushort, 128, true><<<gg, 256, 0, stream>>>(Zbuf, Wb1, Ybuf, n, Mp);
    k_agg128<true><<<4 * nchunk, 256, 0, stream>>>(Ybuf, offs, cnt, esrc, b1, Zbuf, perm, qh + 64, n, nchunk);
    // --- layer 2 (N=64, no relu, fp32 out) ---
    k_gemm_mfma<ushort, 64, true><<<gg, 256, 0, stream>>>(Zbuf, Wb2, Ybuf, n, Mp);
    k_agg64<<<2 * nchunk, 256, 0, stream>>>(Ybuf, offs, cnt, esrc, b2, out, perm, qh + 128, n, nchunk);

    (void)ws_size; (void)n_in; (void)out_size;
}